// Round 1
// baseline (896.984 us; speedup 1.0000x reference)
//
#include <hip/hip_runtime.h>

#define NN 50000
#define EE 800000

typedef __attribute__((ext_vector_type(4))) float f32x4;
typedef __attribute__((ext_vector_type(8))) short bf16x8;

typedef const __attribute__((address_space(1))) void* gas_p;
typedef __attribute__((address_space(3))) void* las_p;

__device__ __forceinline__ float bf2f(unsigned short u) {
  union { unsigned int i; float f; } v; v.i = ((unsigned int)u) << 16; return v.f;
}
__device__ __forceinline__ unsigned short f2bf(float f) {
  union { float f; unsigned int i; } v; v.f = f;
  unsigned int u = v.i;
  return (unsigned short)((u + 0x7FFFu + ((u >> 16) & 1u)) >> 16);
}

// ---------------- workspace layout (bytes, all 256-aligned) ----------------
// x_bf [50000,512]bf16 -> reused as h0 [50000,256]f32 after gcn1 GEMM
constexpr size_t O_XBF  = 0;
constexpr size_t O_H1   = O_XBF + 51200000;   // h1 [50000,512]bf16; reused: g2 (25.6MB) + x2 (25.6MB)
constexpr size_t O_G1   = O_H1  + 51200000;   // g1 [50000,256]bf16
constexpr size_t O_X1   = O_G1  + 25600000;   // x1 [50000,256]bf16
constexpr size_t O_H2   = O_X1  + 25600000;   // h2 [50000,64]bf16
constexpr size_t O_LG   = O_H2  + 6400000;    // Lg [50000,8]f32
constexpr size_t O_TG   = O_LG  + 1600000;    // Tg [50000,8]f32
constexpr size_t O_EWR  = O_TG  + 1600000;    // ew_raw [E]f32; reused as y3 [50000,8]f32
constexpr size_t O_EWS  = O_EWR + 3200000;    // ew_std [E]f32
constexpr size_t O_CSRS = O_EWS + 3200000;    // csr_src [E]i32
constexpr size_t O_CSRW = O_CSRS + 3200000;   // csr_w [E]f32
constexpr size_t O_MW1T = O_CSRW + 3200000;   // 512*512 bf16
constexpr size_t O_W1T  = O_MW1T + 524288;    // 256*512 bf16
constexpr size_t O_W2T  = O_W1T  + 262144;    // 256*256 bf16
constexpr size_t O_MW2T = O_W2T  + 131072;    // 64*512 bf16
constexpr size_t O_DEG  = O_MW2T + 65536;     // [N]f32   <- zero block start
constexpr size_t O_CNT  = O_DEG  + 200192;    // [N]i32
constexpr size_t O_CUR  = O_CNT  + 200192;    // [N]i32
constexpr size_t O_RED  = O_CUR  + 200192;    // 2 doubles <- zero block end
constexpr size_t O_RPT  = O_RED  + 256;       // [N+1]i32
constexpr size_t O_DINV = O_RPT  + 200192;    // [N]f32

// ---------------- conversions ----------------
__global__ __launch_bounds__(256) void conv_f2bf4(const float* __restrict__ in,
                                                  unsigned short* __restrict__ out, int n4) {
  int i = blockIdx.x * 256 + threadIdx.x;
  if (i >= n4) return;
  const float4 v = ((const float4*)in)[i];
  ushort4 o; o.x = f2bf(v.x); o.y = f2bf(v.y); o.z = f2bf(v.z); o.w = f2bf(v.w);
  ((ushort4*)out)[i] = o;
}

__global__ __launch_bounds__(256) void conv_transpose(const float* __restrict__ W,
                                                      unsigned short* __restrict__ Wt,
                                                      int K, int N) {
  int i = blockIdx.x * 256 + threadIdx.x;
  if (i >= K * N) return;
  int k = i / N, n = i - k * N;
  Wt[(size_t)n * K + k] = f2bf(W[i]);
}

// ---------------- bf16 MFMA GEMM: C[M,ldc] = A[M,lda] * Bt[N,K]^T ----------------
// 128x128 tile, BK=32, 4 waves (2x2 of 64x64), global_load_lds w/ XOR kslot swizzle.
template<bool RELU, bool BIAS>
__global__ __launch_bounds__(256)
void gemm_bf16(const unsigned short* __restrict__ A, int lda,
               const unsigned short* __restrict__ Bt,
               const float* __restrict__ bias,
               unsigned short* __restrict__ C, int ldc,
               int M, int N, int K)
{
  __shared__ unsigned short ldsA[128 * 32];
  __shared__ unsigned short ldsB[128 * 32];
  const int tid  = threadIdx.x;
  const int lane = tid & 63;
  const int wid  = tid >> 6;
  const int wm   = (wid >> 1) << 6;
  const int wn   = (wid & 1) << 6;
  const int bm   = blockIdx.x << 7;
  const int bn   = blockIdx.y << 7;

  f32x4 acc[4][4] = {};

  const int srow  = lane >> 2;   // row within 16-row chunk
  const int sslot = lane & 3;    // 16B slot within 64B row

  for (int k0 = 0; k0 < K; k0 += 32) {
    if (k0) __syncthreads();
#pragma unroll
    for (int c = 0; c < 2; ++c) {
      const int chunk = c * 4 + wid;          // 0..7, wave-uniform
      const int row   = chunk * 16 + srow;    // 0..127
      const int ks    = sslot ^ ((row >> 1) & 3);  // swizzled source k-slot
      int ga = bm + row; ga = ga < M ? ga : M - 1;
      int gb = bn + row; gb = gb < N ? gb : N - 1;
      const char* srcA = (const char*)A  + ((size_t)ga * lda + k0) * 2 + ks * 16;
      const char* srcB = (const char*)Bt + ((size_t)gb * K   + k0) * 2 + ks * 16;
      __builtin_amdgcn_global_load_lds((gas_p)srcA, (las_p)(ldsA + chunk * 512), 16, 0, 0);
      __builtin_amdgcn_global_load_lds((gas_p)srcB, (las_p)(ldsB + chunk * 512), 16, 0, 0);
    }
    __syncthreads();

    const int q   = lane >> 4;
    const int r15 = lane & 15;
    bf16x8 af[4], bfr[4];
#pragma unroll
    for (int m = 0; m < 4; ++m) {
      const int ra = wm + m * 16 + r15;
      af[m]  = *(const bf16x8*)(ldsA + ra * 32 + (q ^ ((ra >> 1) & 3)) * 8);
      const int rb = wn + m * 16 + r15;
      bfr[m] = *(const bf16x8*)(ldsB + rb * 32 + (q ^ ((rb >> 1) & 3)) * 8);
    }
#pragma unroll
    for (int m = 0; m < 4; ++m)
#pragma unroll
      for (int n = 0; n < 4; ++n)
        acc[m][n] = __builtin_amdgcn_mfma_f32_16x16x32_bf16(af[m], bfr[n], acc[m][n], 0, 0, 0);
  }

  const int q   = lane >> 4;
  const int r15 = lane & 15;
#pragma unroll
  for (int m = 0; m < 4; ++m) {
#pragma unroll
    for (int n = 0; n < 4; ++n) {
      const int gc = bn + wn + n * 16 + r15;
#pragma unroll
      for (int i = 0; i < 4; ++i) {
        const int gr = bm + wm + m * 16 + q * 4 + i;
        if (gr < M && gc < N) {
          float f = acc[m][n][i];
          if (BIAS) f += bias[gc];
          if (RELU) f = fmaxf(f, 0.f);
          C[(size_t)gr * ldc + gc] = f2bf(f);
        }
      }
    }
  }
}

// ---------------- logits (h2[N,64] @ mw3[64,7] + mb3) and T = L @ relu(2*P) ----------------
__global__ __launch_bounds__(256)
void logits_kernel(const unsigned short* __restrict__ h2, const float* __restrict__ mw3,
                   const float* __restrict__ mb3, const float* __restrict__ par,
                   float* __restrict__ Lg, float* __restrict__ Tg)
{
  __shared__ float w[64 * 8];
  __shared__ float P[64];
  int tid = threadIdx.x;
  for (int i = tid; i < 512; i += 256) {
    int k = i >> 3, c = i & 7;
    w[i] = (c < 7) ? mw3[k * 7 + c] : 0.f;
  }
  if (tid < 64) {
    int d = tid >> 3, c = tid & 7;
    P[tid] = (d < 7 && c < 7) ? fmaxf(2.0f * par[d * 7 + c], 0.f) : 0.f;
  }
  __syncthreads();
  int n = blockIdx.x * 256 + tid;
  if (n >= NN) return;
  const unsigned short* hr = h2 + (size_t)n * 64;
  f32x4 L0 = {0,0,0,0}, L1 = {0,0,0,0};
  for (int k = 0; k < 64; k += 4) {
    ushort4 v = *(const ushort4*)(hr + k);
    float xs[4] = {bf2f(v.x), bf2f(v.y), bf2f(v.z), bf2f(v.w)};
#pragma unroll
    for (int j = 0; j < 4; ++j) {
      L0 += xs[j] * *(const f32x4*)&w[(k + j) * 8];
      L1 += xs[j] * *(const f32x4*)&w[(k + j) * 8 + 4];
    }
  }
  float Ls[8] = {L0[0], L0[1], L0[2], L0[3], L1[0], L1[1], L1[2], 0.f};
#pragma unroll
  for (int c = 0; c < 7; ++c) Ls[c] += mb3[c];
  f32x4 T0 = {0,0,0,0}, T1 = {0,0,0,0};
#pragma unroll
  for (int d = 0; d < 7; ++d) {
    T0 += Ls[d] * *(const f32x4*)&P[d * 8];
    T1 += Ls[d] * *(const f32x4*)&P[d * 8 + 4];
  }
  f32x4 o0 = {Ls[0], Ls[1], Ls[2], Ls[3]};
  f32x4 o1 = {Ls[4], Ls[5], Ls[6], 0.f};
  *(f32x4*)(Lg + (size_t)n * 8)     = o0;
  *(f32x4*)(Lg + (size_t)n * 8 + 4) = o1;
  *(f32x4*)(Tg + (size_t)n * 8)     = T0;
  *(f32x4*)(Tg + (size_t)n * 8 + 4) = T1;
}

// ---------------- edge pass 1: raw ew, dest histogram, sum/sumsq (double) ----------------
__global__ __launch_bounds__(256)
void edge1_kernel(const int* __restrict__ row, const int* __restrict__ col,
                  const float* __restrict__ Lg, const float* __restrict__ Tg,
                  float* __restrict__ ew_raw, int* __restrict__ cnt,
                  double* __restrict__ red)
{
  int e = blockIdx.x * 256 + threadIdx.x;
  double s = 0.0, s2 = 0.0;
  if (e < EE) {
    int r = row[e], c = col[e];
    float4 a0 = *(const float4*)(Lg + (size_t)r * 8);
    float4 a1 = *(const float4*)(Lg + (size_t)r * 8 + 4);
    float4 b0 = *(const float4*)(Tg + (size_t)c * 8);
    float4 b1 = *(const float4*)(Tg + (size_t)c * 8 + 4);
    float v = a0.x*b0.x + a0.y*b0.y + a0.z*b0.z + a0.w*b0.w
            + a1.x*b1.x + a1.y*b1.y + a1.z*b1.z + a1.w*b1.w;
    ew_raw[e] = v;
    atomicAdd(&cnt[c], 1);
    s = (double)v; s2 = (double)v * (double)v;
  }
  for (int off = 32; off; off >>= 1) {
    s  += __shfl_down(s, off);
    s2 += __shfl_down(s2, off);
  }
  if ((threadIdx.x & 63) == 0) {
    atomicAdd(&red[0], s);
    atomicAdd(&red[1], s2);
  }
}

// ---------------- edge pass 2: standardize, accumulate deg ----------------
__global__ __launch_bounds__(256)
void edge2_kernel(const float* __restrict__ ew_raw, const int* __restrict__ col,
                  const double* __restrict__ red,
                  float* __restrict__ ew_std, float* __restrict__ deg)
{
  int e = blockIdx.x * 256 + threadIdx.x;
  if (e >= EE) return;
  double mean = red[0] / (double)EE;
  double var  = (red[1] - (double)EE * mean * mean) / (double)(EE - 1);
  double scl  = sqrt(1e-4 / var);
  float v = (float)(((double)ew_raw[e] - mean) * scl) + 1.0f;
  ew_std[e] = v;
  atomicAdd(&deg[col[e]], v);
}

__global__ __launch_bounds__(256)
void dinv_kernel(const float* __restrict__ deg, float* __restrict__ dinv)
{
  int n = blockIdx.x * 256 + threadIdx.x;
  if (n >= NN) return;
  float d = deg[n] + 1.0f;  // self-loop weight 1
  dinv[n] = d > 0.f ? 1.0f / sqrtf(fmaxf(d, 1e-12f)) : 0.f;
}

// ---------------- exclusive scan of cnt -> rowptr (single block) ----------------
__global__ __launch_bounds__(1024)
void scan_kernel(const int* __restrict__ cnt, int* __restrict__ rowptr)
{
  __shared__ int sh[1024];
  __shared__ int carry;
  int tid = threadIdx.x;
  if (tid == 0) { carry = 0; rowptr[0] = 0; }
  __syncthreads();
  for (int base = 0; base < NN; base += 1024) {
    int i = base + tid;
    sh[tid] = (i < NN) ? cnt[i] : 0;
    __syncthreads();
    for (int off = 1; off < 1024; off <<= 1) {
      int t = (tid >= off) ? sh[tid - off] : 0;
      __syncthreads();
      sh[tid] += t;
      __syncthreads();
    }
    if (i < NN) rowptr[i + 1] = carry + sh[tid];
    __syncthreads();
    if (tid == 0) carry += sh[1023];
    __syncthreads();
  }
}

// ---------------- edge pass 3: fill CSR (by destination) with edge norms ----------------
__global__ __launch_bounds__(256)
void edge3_kernel(const int* __restrict__ row, const int* __restrict__ col,
                  const float* __restrict__ ew_std, const float* __restrict__ dinv,
                  const int* __restrict__ rowptr, int* __restrict__ cursor,
                  int* __restrict__ csr_src, float* __restrict__ csr_w)
{
  int e = blockIdx.x * 256 + threadIdx.x;
  if (e >= EE) return;
  int r = row[e], c = col[e];
  float w = dinv[r] * ew_std[e] * dinv[c];
  int pos = atomicAdd(&cursor[c], 1);
  int idx = rowptr[c] + pos;
  csr_src[idx] = r;
  csr_w[idx]   = w;
}

// ---------------- dim-256 aggregation: one wave per node ----------------
// MODE 0: h0 = agg(g1)+b (f32), x1 = bf16(relu(h0))
// MODE 1: x2 = bf16(relu(agg(g2)+b) + h0)
template<int MODE>
__global__ __launch_bounds__(256)
void agg256_kernel(const int* __restrict__ rowptr, const int* __restrict__ csr_src,
                   const float* __restrict__ csr_w, const unsigned short* __restrict__ gsrc,
                   const float* __restrict__ dinv, const float* __restrict__ bias,
                   const float* __restrict__ h0in, float* __restrict__ h0out,
                   unsigned short* __restrict__ xout)
{
  int n = blockIdx.x * 4 + (threadIdx.x >> 6);
  if (n >= NN) return;
  int l = threadIdx.x & 63;
  float a0 = 0.f, a1 = 0.f, a2 = 0.f, a3 = 0.f;
  int s = rowptr[n], e = rowptr[n + 1];
  for (int i = s; i < e; ++i) {
    int src = csr_src[i];
    float w = csr_w[i];
    ushort4 v = *(const ushort4*)(gsrc + (size_t)src * 256 + (l << 2));
    a0 += w * bf2f(v.x); a1 += w * bf2f(v.y);
    a2 += w * bf2f(v.z); a3 += w * bf2f(v.w);
  }
  float wd = dinv[n]; wd *= wd;   // self-loop: dinv^2 * 1
  {
    ushort4 v = *(const ushort4*)(gsrc + (size_t)n * 256 + (l << 2));
    a0 += wd * bf2f(v.x); a1 += wd * bf2f(v.y);
    a2 += wd * bf2f(v.z); a3 += wd * bf2f(v.w);
  }
  size_t o = (size_t)n * 256 + (l << 2);
  float4 b = *(const float4*)(bias + (l << 2));
  a0 += b.x; a1 += b.y; a2 += b.z; a3 += b.w;
  if (MODE == 0) {
    float4 h; h.x = a0; h.y = a1; h.z = a2; h.w = a3;
    *(float4*)(h0out + o) = h;
    ushort4 xo;
    xo.x = f2bf(fmaxf(a0, 0.f)); xo.y = f2bf(fmaxf(a1, 0.f));
    xo.z = f2bf(fmaxf(a2, 0.f)); xo.w = f2bf(fmaxf(a3, 0.f));
    *(ushort4*)(xout + o) = xo;
  } else {
    float4 h = *(const float4*)(h0in + o);
    ushort4 xo;
    xo.x = f2bf(fmaxf(a0, 0.f) + h.x); xo.y = f2bf(fmaxf(a1, 0.f) + h.y);
    xo.z = f2bf(fmaxf(a2, 0.f) + h.z); xo.w = f2bf(fmaxf(a3, 0.f) + h.w);
    *(ushort4*)(xout + o) = xo;
  }
}

// ---------------- y3[N,8] = x2[N,256] @ W3[256,7] (fp32 W, col 7 zero) ----------------
__global__ __launch_bounds__(256)
void gemv7_kernel(const unsigned short* __restrict__ x2, const float* __restrict__ W3,
                  float* __restrict__ y3)
{
  __shared__ float w[256 * 8];
  int tid = threadIdx.x;
  for (int i = tid; i < 2048; i += 256) {
    int k = i >> 3, c = i & 7;
    w[i] = (c < 7) ? W3[k * 7 + c] : 0.f;
  }
  __syncthreads();
  int n = blockIdx.x * 256 + tid;
  if (n >= NN) return;
  const unsigned short* xr = x2 + (size_t)n * 256;
  f32x4 accLo = {0,0,0,0}, accHi = {0,0,0,0};
  for (int k = 0; k < 256; k += 4) {
    ushort4 v = *(const ushort4*)(xr + k);
    float xs[4] = {bf2f(v.x), bf2f(v.y), bf2f(v.z), bf2f(v.w)};
#pragma unroll
    for (int j = 0; j < 4; ++j) {
      accLo += xs[j] * *(const f32x4*)&w[(k + j) * 8];
      accHi += xs[j] * *(const f32x4*)&w[(k + j) * 8 + 4];
    }
  }
  *(f32x4*)(y3 + (size_t)n * 8)     = accLo;
  *(f32x4*)(y3 + (size_t)n * 8 + 4) = accHi;
}

// ---------------- dim-7 aggregation: 8 lanes per node ----------------
__global__ __launch_bounds__(256)
void agg7_kernel(const int* __restrict__ rowptr, const int* __restrict__ csr_src,
                 const float* __restrict__ csr_w, const float* __restrict__ y3,
                 const float* __restrict__ dinv, const float* __restrict__ b3,
                 float* __restrict__ out)
{
  int n = blockIdx.x * 32 + (threadIdx.x >> 3);
  if (n >= NN) return;
  int j = threadIdx.x & 7;
  float acc = 0.f;
  int s = rowptr[n], e = rowptr[n + 1];
  for (int i = s; i < e; ++i) {
    int src = csr_src[i];
    float w = csr_w[i];
    acc += w * y3[(size_t)src * 8 + j];
  }
  float wd = dinv[n]; wd *= wd;
  acc += wd * y3[(size_t)n * 8 + j];
  if (j < 7) out[(size_t)n * 7 + j] = acc + b3[j];
}

// ---------------- host ----------------
extern "C" void kernel_launch(void* const* d_in, const int* in_sizes, int n_in,
                              void* d_out, int out_size, void* d_ws, size_t ws_size,
                              hipStream_t stream)
{
  const float* x   = (const float*)d_in[0];
  const int*   ei  = (const int*)d_in[1];
  const float* W1  = (const float*)d_in[2];
  const float* b1  = (const float*)d_in[3];
  const float* W2  = (const float*)d_in[4];
  const float* b2  = (const float*)d_in[5];
  const float* W3  = (const float*)d_in[6];
  const float* b3  = (const float*)d_in[7];
  const float* mw1 = (const float*)d_in[8];
  const float* mb1 = (const float*)d_in[9];
  const float* mw2 = (const float*)d_in[10];
  const float* mb2 = (const float*)d_in[11];
  const float* mw3 = (const float*)d_in[12];
  const float* mb3 = (const float*)d_in[13];
  const float* par = (const float*)d_in[14];
  const int* row = ei;
  const int* col = ei + EE;
  float* out = (float*)d_out;

  char* ws = (char*)d_ws;
  unsigned short* x_bf  = (unsigned short*)(ws + O_XBF);
  float*          h0    = (float*)(ws + O_XBF);            // reuse after gcn1 GEMM
  unsigned short* h1_bf = (unsigned short*)(ws + O_H1);
  unsigned short* g2_bf = (unsigned short*)(ws + O_H1);    // reuse (h1 dead)
  unsigned short* x2_bf = (unsigned short*)(ws + O_H1 + 25600000);
  unsigned short* g1_bf = (unsigned short*)(ws + O_G1);
  unsigned short* x1_bf = (unsigned short*)(ws + O_X1);
  unsigned short* h2_bf = (unsigned short*)(ws + O_H2);
  float* Lg      = (float*)(ws + O_LG);
  float* Tg      = (float*)(ws + O_TG);
  float* ew_raw  = (float*)(ws + O_EWR);
  float* y3      = (float*)(ws + O_EWR);                   // reuse (ew_raw dead)
  float* ew_std  = (float*)(ws + O_EWS);
  int*   csr_src = (int*)(ws + O_CSRS);
  float* csr_w   = (float*)(ws + O_CSRW);
  unsigned short* mw1t = (unsigned short*)(ws + O_MW1T);
  unsigned short* w1t  = (unsigned short*)(ws + O_W1T);
  unsigned short* w2t  = (unsigned short*)(ws + O_W2T);
  unsigned short* mw2t = (unsigned short*)(ws + O_MW2T);
  float*  deg    = (float*)(ws + O_DEG);
  int*    cnt    = (int*)(ws + O_CNT);
  int*    cursor = (int*)(ws + O_CUR);
  double* red    = (double*)(ws + O_RED);
  int*    rowptr = (int*)(ws + O_RPT);
  float*  dinv   = (float*)(ws + O_DINV);

  // zero: deg, cnt, cursor, red (contiguous)
  hipMemsetAsync(ws + O_DEG, 0, 3 * 200192 + 256, stream);

  // fp32 -> bf16 conversions
  conv_f2bf4<<<25000, 256, 0, stream>>>(x, x_bf, NN * 512 / 4);
  conv_transpose<<<1024, 256, 0, stream>>>(mw1, mw1t, 512, 512);
  conv_transpose<<<512, 256, 0, stream>>>(W1, w1t, 512, 256);
  conv_transpose<<<256, 256, 0, stream>>>(W2, w2t, 256, 256);
  conv_transpose<<<128, 256, 0, stream>>>(mw2, mw2t, 512, 64);

  // pseudo-MLP
  gemm_bf16<true,  true ><<<dim3(391, 4), 256, 0, stream>>>(x_bf, 512, mw1t, mb1, h1_bf, 512, NN, 512, 512);
  gemm_bf16<true,  true ><<<dim3(391, 1), 256, 0, stream>>>(h1_bf, 512, mw2t, mb2, h2_bf, 64, NN, 64, 512);
  logits_kernel<<<196, 256, 0, stream>>>(h2_bf, mw3, mb3, par, Lg, Tg);

  // edge weights + CSR
  edge1_kernel<<<3125, 256, 0, stream>>>(row, col, Lg, Tg, ew_raw, cnt, red);
  edge2_kernel<<<3125, 256, 0, stream>>>(ew_raw, col, red, ew_std, deg);
  dinv_kernel<<<196, 256, 0, stream>>>(deg, dinv);
  scan_kernel<<<1, 1024, 0, stream>>>(cnt, rowptr);
  edge3_kernel<<<3125, 256, 0, stream>>>(row, col, ew_std, dinv, rowptr, cursor, csr_src, csr_w);

  // GCN layer 0
  gemm_bf16<false, false><<<dim3(391, 2), 256, 0, stream>>>(x_bf, 512, w1t, nullptr, g1_bf, 256, NN, 256, 512);
  agg256_kernel<0><<<12500, 256, 0, stream>>>(rowptr, csr_src, csr_w, g1_bf, dinv, b1, nullptr, h0, x1_bf);
  // GCN layer 1 (+residual h0)
  gemm_bf16<false, false><<<dim3(391, 2), 256, 0, stream>>>(x1_bf, 256, w2t, nullptr, g2_bf, 256, NN, 256, 256);
  agg256_kernel<1><<<12500, 256, 0, stream>>>(rowptr, csr_src, csr_w, g2_bf, dinv, b2, h0, nullptr, x2_bf);
  // GCN layer 2 (GEMM first, aggregate in dim 7)
  gemv7_kernel<<<196, 256, 0, stream>>>(x2_bf, W3, y3);
  agg7_kernel<<<1563, 256, 0, stream>>>(rowptr, csr_src, csr_w, y3, dinv, b3, out);
}

// Round 2
// 639.638 us; speedup vs baseline: 1.4023x; 1.4023x over previous
//
#include <hip/hip_runtime.h>

#define NN 50000
#define EE 800000
#define NB_EDGE 3125   // ceil(EE/256)

typedef __attribute__((ext_vector_type(4))) float f32x4;
typedef __attribute__((ext_vector_type(8))) short bf16x8;

typedef const __attribute__((address_space(1))) void* gas_p;
typedef __attribute__((address_space(3))) void* las_p;

__device__ __forceinline__ float bf2f(unsigned short u) {
  union { unsigned int i; float f; } v; v.i = ((unsigned int)u) << 16; return v.f;
}
__device__ __forceinline__ unsigned short f2bf(float f) {
  union { float f; unsigned int i; } v; v.f = f;
  unsigned int u = v.i;
  return (unsigned short)((u + 0x7FFFu + ((u >> 16) & 1u)) >> 16);
}

// ---------------- workspace layout (bytes, all 256-aligned) ----------------
constexpr size_t O_XBF  = 0;
constexpr size_t O_H1   = O_XBF + 51200000;   // h1 [50000,512]bf16; reused: g2 (25.6MB) + x2 (25.6MB)
constexpr size_t O_G1   = O_H1  + 51200000;   // g1 [50000,256]bf16
constexpr size_t O_X1   = O_G1  + 25600000;   // x1 [50000,256]bf16
constexpr size_t O_H2   = O_X1  + 25600000;   // h2 [50000,64]bf16
constexpr size_t O_LG   = O_H2  + 6400000;    // Lg [50000,8]f32
constexpr size_t O_TG   = O_LG  + 1600000;    // Tg [50000,8]f32
constexpr size_t O_EWR  = O_TG  + 1600000;    // ew_raw [E]f32; reused as y3 [50000,8]f32
constexpr size_t O_EWS  = O_EWR + 3200000;    // ew_std [E]f32
constexpr size_t O_CSRS = O_EWS + 3200000;    // csr_src [E]i32  (aliased: edge1 partials, dead by edge3)
constexpr size_t O_CSRW = O_CSRS + 3200000;   // csr_w [E]f32
constexpr size_t O_MW1T = O_CSRW + 3200000;   // 512*512 bf16
constexpr size_t O_W1T  = O_MW1T + 524288;    // 256*512 bf16
constexpr size_t O_W2T  = O_W1T  + 262144;    // 256*256 bf16
constexpr size_t O_MW2T = O_W2T  + 131072;    // 64*512 bf16
constexpr size_t O_DEG  = O_MW2T + 65536;     // [N]f32   <- zero block start
constexpr size_t O_CNT  = O_DEG  + 200192;    // [N]i32
constexpr size_t O_CUR  = O_CNT  + 200192;    // [N]i32
constexpr size_t O_RED  = O_CUR  + 200192;    // 2 doubles <- zero block end
constexpr size_t O_RPT  = O_RED  + 256;       // [N+1]i32
constexpr size_t O_DINV = O_RPT  + 200192;    // [N]f32

// ---------------- conversions ----------------
__global__ __launch_bounds__(256) void conv_f2bf4(const float* __restrict__ in,
                                                  unsigned short* __restrict__ out, int n4) {
  int i = blockIdx.x * 256 + threadIdx.x;
  if (i >= n4) return;
  const float4 v = ((const float4*)in)[i];
  ushort4 o; o.x = f2bf(v.x); o.y = f2bf(v.y); o.z = f2bf(v.z); o.w = f2bf(v.w);
  ((ushort4*)out)[i] = o;
}

__global__ __launch_bounds__(256) void conv_transpose(const float* __restrict__ W,
                                                      unsigned short* __restrict__ Wt,
                                                      int K, int N) {
  int i = blockIdx.x * 256 + threadIdx.x;
  if (i >= K * N) return;
  int k = i / N, n = i - k * N;
  Wt[(size_t)n * K + k] = f2bf(W[i]);
}

// ---------------- bf16 MFMA GEMM: C[M,ldc] = A[M,lda] * Bt[N,K]^T ----------------
template<bool RELU, bool BIAS>
__global__ __launch_bounds__(256)
void gemm_bf16(const unsigned short* __restrict__ A, int lda,
               const unsigned short* __restrict__ Bt,
               const float* __restrict__ bias,
               unsigned short* __restrict__ C, int ldc,
               int M, int N, int K)
{
  __shared__ unsigned short ldsA[128 * 32];
  __shared__ unsigned short ldsB[128 * 32];
  const int tid  = threadIdx.x;
  const int lane = tid & 63;
  const int wid  = tid >> 6;
  const int wm   = (wid >> 1) << 6;
  const int wn   = (wid & 1) << 6;
  const int bm   = blockIdx.x << 7;
  const int bn   = blockIdx.y << 7;

  f32x4 acc[4][4] = {};

  const int srow  = lane >> 2;
  const int sslot = lane & 3;

  for (int k0 = 0; k0 < K; k0 += 32) {
    if (k0) __syncthreads();
#pragma unroll
    for (int c = 0; c < 2; ++c) {
      const int chunk = c * 4 + wid;
      const int row   = chunk * 16 + srow;
      const int ks    = sslot ^ ((row >> 1) & 3);
      int ga = bm + row; ga = ga < M ? ga : M - 1;
      int gb = bn + row; gb = gb < N ? gb : N - 1;
      const char* srcA = (const char*)A  + ((size_t)ga * lda + k0) * 2 + ks * 16;
      const char* srcB = (const char*)Bt + ((size_t)gb * K   + k0) * 2 + ks * 16;
      __builtin_amdgcn_global_load_lds((gas_p)srcA, (las_p)(ldsA + chunk * 512), 16, 0, 0);
      __builtin_amdgcn_global_load_lds((gas_p)srcB, (las_p)(ldsB + chunk * 512), 16, 0, 0);
    }
    __syncthreads();

    const int q   = lane >> 4;
    const int r15 = lane & 15;
    bf16x8 af[4], bfr[4];
#pragma unroll
    for (int m = 0; m < 4; ++m) {
      const int ra = wm + m * 16 + r15;
      af[m]  = *(const bf16x8*)(ldsA + ra * 32 + (q ^ ((ra >> 1) & 3)) * 8);
      const int rb = wn + m * 16 + r15;
      bfr[m] = *(const bf16x8*)(ldsB + rb * 32 + (q ^ ((rb >> 1) & 3)) * 8);
    }
#pragma unroll
    for (int m = 0; m < 4; ++m)
#pragma unroll
      for (int n = 0; n < 4; ++n)
        acc[m][n] = __builtin_amdgcn_mfma_f32_16x16x32_bf16(af[m], bfr[n], acc[m][n], 0, 0, 0);
  }

  const int q   = lane >> 4;
  const int r15 = lane & 15;
#pragma unroll
  for (int m = 0; m < 4; ++m) {
#pragma unroll
    for (int n = 0; n < 4; ++n) {
      const int gc = bn + wn + n * 16 + r15;
#pragma unroll
      for (int i = 0; i < 4; ++i) {
        const int gr = bm + wm + m * 16 + q * 4 + i;
        if (gr < M && gc < N) {
          float f = acc[m][n][i];
          if (BIAS) f += bias[gc];
          if (RELU) f = fmaxf(f, 0.f);
          C[(size_t)gr * ldc + gc] = f2bf(f);
        }
      }
    }
  }
}

// ---------------- logits (h2[N,64] @ mw3[64,7] + mb3) and T = L @ relu(2*P) ----------------
__global__ __launch_bounds__(256)
void logits_kernel(const unsigned short* __restrict__ h2, const float* __restrict__ mw3,
                   const float* __restrict__ mb3, const float* __restrict__ par,
                   float* __restrict__ Lg, float* __restrict__ Tg)
{
  __shared__ float w[64 * 8];
  __shared__ float P[64];
  int tid = threadIdx.x;
  for (int i = tid; i < 512; i += 256) {
    int k = i >> 3, c = i & 7;
    w[i] = (c < 7) ? mw3[k * 7 + c] : 0.f;
  }
  if (tid < 64) {
    int d = tid >> 3, c = tid & 7;
    P[tid] = (d < 7 && c < 7) ? fmaxf(2.0f * par[d * 7 + c], 0.f) : 0.f;
  }
  __syncthreads();
  int n = blockIdx.x * 256 + tid;
  if (n >= NN) return;
  const unsigned short* hr = h2 + (size_t)n * 64;
  f32x4 L0 = {0,0,0,0}, L1 = {0,0,0,0};
  for (int k = 0; k < 64; k += 4) {
    ushort4 v = *(const ushort4*)(hr + k);
    float xs[4] = {bf2f(v.x), bf2f(v.y), bf2f(v.z), bf2f(v.w)};
#pragma unroll
    for (int j = 0; j < 4; ++j) {
      L0 += xs[j] * *(const f32x4*)&w[(k + j) * 8];
      L1 += xs[j] * *(const f32x4*)&w[(k + j) * 8 + 4];
    }
  }
  float Ls[8] = {L0[0], L0[1], L0[2], L0[3], L1[0], L1[1], L1[2], 0.f};
#pragma unroll
  for (int c = 0; c < 7; ++c) Ls[c] += mb3[c];
  f32x4 T0 = {0,0,0,0}, T1 = {0,0,0,0};
#pragma unroll
  for (int d = 0; d < 7; ++d) {
    T0 += Ls[d] * *(const f32x4*)&P[d * 8];
    T1 += Ls[d] * *(const f32x4*)&P[d * 8 + 4];
  }
  f32x4 o0 = {Ls[0], Ls[1], Ls[2], Ls[3]};
  f32x4 o1 = {Ls[4], Ls[5], Ls[6], 0.f};
  *(f32x4*)(Lg + (size_t)n * 8)     = o0;
  *(f32x4*)(Lg + (size_t)n * 8 + 4) = o1;
  *(f32x4*)(Tg + (size_t)n * 8)     = T0;
  *(f32x4*)(Tg + (size_t)n * 8 + 4) = T1;
}

// ---------------- edge pass 1: raw ew, dest histogram, per-block sum/sumsq partials ----------------
__global__ __launch_bounds__(256)
void edge1_kernel(const int* __restrict__ row, const int* __restrict__ col,
                  const float* __restrict__ Lg, const float* __restrict__ Tg,
                  float* __restrict__ ew_raw, int* __restrict__ cnt,
                  double* __restrict__ part)     // part[0..NB), part[NB..2NB)
{
  __shared__ double shs[4], shs2[4];
  int e = blockIdx.x * 256 + threadIdx.x;
  double s = 0.0, s2 = 0.0;
  if (e < EE) {
    int r = row[e], c = col[e];
    float4 a0 = *(const float4*)(Lg + (size_t)r * 8);
    float4 a1 = *(const float4*)(Lg + (size_t)r * 8 + 4);
    float4 b0 = *(const float4*)(Tg + (size_t)c * 8);
    float4 b1 = *(const float4*)(Tg + (size_t)c * 8 + 4);
    float v = a0.x*b0.x + a0.y*b0.y + a0.z*b0.z + a0.w*b0.w
            + a1.x*b1.x + a1.y*b1.y + a1.z*b1.z + a1.w*b1.w;
    ew_raw[e] = v;
    atomicAdd(&cnt[c], 1);
    s = (double)v; s2 = (double)v * (double)v;
  }
  for (int off = 32; off; off >>= 1) {
    s  += __shfl_down(s, off);
    s2 += __shfl_down(s2, off);
  }
  int wv = threadIdx.x >> 6;
  if ((threadIdx.x & 63) == 0) { shs[wv] = s; shs2[wv] = s2; }
  __syncthreads();
  if (threadIdx.x == 0) {
    part[blockIdx.x]           = shs[0] + shs[1] + shs[2] + shs[3];
    part[NB_EDGE + blockIdx.x] = shs2[0] + shs2[1] + shs2[2] + shs2[3];
  }
}

// ---------------- reduce edge1 partials -> red[0]=sum, red[1]=sumsq ----------------
__global__ __launch_bounds__(1024)
void redpart_kernel(const double* __restrict__ part, double* __restrict__ red)
{
  __shared__ double sh[16][2];
  int tid = threadIdx.x;
  double s = 0.0, s2 = 0.0;
  for (int i = tid; i < NB_EDGE; i += 1024) {
    s  += part[i];
    s2 += part[NB_EDGE + i];
  }
  for (int off = 32; off; off >>= 1) {
    s  += __shfl_down(s, off);
    s2 += __shfl_down(s2, off);
  }
  if ((tid & 63) == 0) { sh[tid >> 6][0] = s; sh[tid >> 6][1] = s2; }
  __syncthreads();
  if (tid == 0) {
    double a = 0.0, b = 0.0;
    for (int i = 0; i < 16; ++i) { a += sh[i][0]; b += sh[i][1]; }
    red[0] = a; red[1] = b;
  }
}

// ---------------- edge pass 2: standardize, accumulate deg ----------------
__global__ __launch_bounds__(256)
void edge2_kernel(const float* __restrict__ ew_raw, const int* __restrict__ col,
                  const double* __restrict__ red,
                  float* __restrict__ ew_std, float* __restrict__ deg)
{
  int e = blockIdx.x * 256 + threadIdx.x;
  if (e >= EE) return;
  double mean = red[0] / (double)EE;
  double var  = (red[1] - (double)EE * mean * mean) / (double)(EE - 1);
  double scl  = sqrt(1e-4 / var);
  float v = (float)(((double)ew_raw[e] - mean) * scl) + 1.0f;
  ew_std[e] = v;
  atomicAdd(&deg[col[e]], v);
}

__global__ __launch_bounds__(256)
void dinv_kernel(const float* __restrict__ deg, float* __restrict__ dinv)
{
  int n = blockIdx.x * 256 + threadIdx.x;
  if (n >= NN) return;
  float d = deg[n] + 1.0f;  // self-loop weight 1
  dinv[n] = d > 0.f ? 1.0f / sqrtf(fmaxf(d, 1e-12f)) : 0.f;
}

// ---------------- exclusive scan of cnt -> rowptr (single block, 20 barriers) ----------------
__global__ __launch_bounds__(1024)
void scan_kernel(const int* __restrict__ cnt, int* __restrict__ rowptr)
{
  constexpr int CH = 49;   // 1024*49 = 50176 >= NN
  __shared__ int sh[1024];
  int tid  = threadIdx.x;
  int base = tid * CH;
  int sum = 0;
  for (int i = 0; i < CH; ++i) {
    int idx = base + i;
    if (idx < NN) sum += cnt[idx];
  }
  sh[tid] = sum;
  __syncthreads();
  for (int off = 1; off < 1024; off <<= 1) {
    int t = (tid >= off) ? sh[tid - off] : 0;
    __syncthreads();
    sh[tid] += t;
    __syncthreads();
  }
  int run = (tid > 0) ? sh[tid - 1] : 0;   // exclusive prefix of this thread's chunk
  if (tid == 0) rowptr[0] = 0;
  for (int i = 0; i < CH; ++i) {
    int idx = base + i;
    if (idx < NN) { run += cnt[idx]; rowptr[idx + 1] = run; }
  }
}

// ---------------- edge pass 3: fill CSR (by destination) with edge norms ----------------
__global__ __launch_bounds__(256)
void edge3_kernel(const int* __restrict__ row, const int* __restrict__ col,
                  const float* __restrict__ ew_std, const float* __restrict__ dinv,
                  const int* __restrict__ rowptr, int* __restrict__ cursor,
                  int* __restrict__ csr_src, float* __restrict__ csr_w)
{
  int e = blockIdx.x * 256 + threadIdx.x;
  if (e >= EE) return;
  int r = row[e], c = col[e];
  float w = dinv[r] * ew_std[e] * dinv[c];
  int pos = atomicAdd(&cursor[c], 1);
  int idx = rowptr[c] + pos;
  csr_src[idx] = r;
  csr_w[idx]   = w;
}

// ---------------- dim-256 aggregation: one wave per node ----------------
template<int MODE>
__global__ __launch_bounds__(256)
void agg256_kernel(const int* __restrict__ rowptr, const int* __restrict__ csr_src,
                   const float* __restrict__ csr_w, const unsigned short* __restrict__ gsrc,
                   const float* __restrict__ dinv, const float* __restrict__ bias,
                   const float* __restrict__ h0in, float* __restrict__ h0out,
                   unsigned short* __restrict__ xout)
{
  int n = blockIdx.x * 4 + (threadIdx.x >> 6);
  if (n >= NN) return;
  int l = threadIdx.x & 63;
  float a0 = 0.f, a1 = 0.f, a2 = 0.f, a3 = 0.f;
  int s = rowptr[n], e = rowptr[n + 1];
  for (int i = s; i < e; ++i) {
    int src = csr_src[i];
    float w = csr_w[i];
    ushort4 v = *(const ushort4*)(gsrc + (size_t)src * 256 + (l << 2));
    a0 += w * bf2f(v.x); a1 += w * bf2f(v.y);
    a2 += w * bf2f(v.z); a3 += w * bf2f(v.w);
  }
  float wd = dinv[n]; wd *= wd;
  {
    ushort4 v = *(const ushort4*)(gsrc + (size_t)n * 256 + (l << 2));
    a0 += wd * bf2f(v.x); a1 += wd * bf2f(v.y);
    a2 += wd * bf2f(v.z); a3 += wd * bf2f(v.w);
  }
  size_t o = (size_t)n * 256 + (l << 2);
  float4 b = *(const float4*)(bias + (l << 2));
  a0 += b.x; a1 += b.y; a2 += b.z; a3 += b.w;
  if (MODE == 0) {
    float4 h; h.x = a0; h.y = a1; h.z = a2; h.w = a3;
    *(float4*)(h0out + o) = h;
    ushort4 xo;
    xo.x = f2bf(fmaxf(a0, 0.f)); xo.y = f2bf(fmaxf(a1, 0.f));
    xo.z = f2bf(fmaxf(a2, 0.f)); xo.w = f2bf(fmaxf(a3, 0.f));
    *(ushort4*)(xout + o) = xo;
  } else {
    float4 h = *(const float4*)(h0in + o);
    ushort4 xo;
    xo.x = f2bf(fmaxf(a0, 0.f) + h.x); xo.y = f2bf(fmaxf(a1, 0.f) + h.y);
    xo.z = f2bf(fmaxf(a2, 0.f) + h.z); xo.w = f2bf(fmaxf(a3, 0.f) + h.w);
    *(ushort4*)(xout + o) = xo;
  }
}

// ---------------- y3[N,8] = x2[N,256] @ W3[256,7] ----------------
__global__ __launch_bounds__(256)
void gemv7_kernel(const unsigned short* __restrict__ x2, const float* __restrict__ W3,
                  float* __restrict__ y3)
{
  __shared__ float w[256 * 8];
  int tid = threadIdx.x;
  for (int i = tid; i < 2048; i += 256) {
    int k = i >> 3, c = i & 7;
    w[i] = (c < 7) ? W3[k * 7 + c] : 0.f;
  }
  __syncthreads();
  int n = blockIdx.x * 256 + tid;
  if (n >= NN) return;
  const unsigned short* xr = x2 + (size_t)n * 256;
  f32x4 accLo = {0,0,0,0}, accHi = {0,0,0,0};
  for (int k = 0; k < 256; k += 4) {
    ushort4 v = *(const ushort4*)(xr + k);
    float xs[4] = {bf2f(v.x), bf2f(v.y), bf2f(v.z), bf2f(v.w)};
#pragma unroll
    for (int j = 0; j < 4; ++j) {
      accLo += xs[j] * *(const f32x4*)&w[(k + j) * 8];
      accHi += xs[j] * *(const f32x4*)&w[(k + j) * 8 + 4];
    }
  }
  *(f32x4*)(y3 + (size_t)n * 8)     = accLo;
  *(f32x4*)(y3 + (size_t)n * 8 + 4) = accHi;
}

// ---------------- dim-7 aggregation: 8 lanes per node ----------------
__global__ __launch_bounds__(256)
void agg7_kernel(const int* __restrict__ rowptr, const int* __restrict__ csr_src,
                 const float* __restrict__ csr_w, const float* __restrict__ y3,
                 const float* __restrict__ dinv, const float* __restrict__ b3,
                 float* __restrict__ out)
{
  int n = blockIdx.x * 32 + (threadIdx.x >> 3);
  if (n >= NN) return;
  int j = threadIdx.x & 7;
  float acc = 0.f;
  int s = rowptr[n], e = rowptr[n + 1];
  for (int i = s; i < e; ++i) {
    int src = csr_src[i];
    float w = csr_w[i];
    acc += w * y3[(size_t)src * 8 + j];
  }
  float wd = dinv[n]; wd *= wd;
  acc += wd * y3[(size_t)n * 8 + j];
  if (j < 7) out[(size_t)n * 7 + j] = acc + b3[j];
}

// ---------------- host ----------------
extern "C" void kernel_launch(void* const* d_in, const int* in_sizes, int n_in,
                              void* d_out, int out_size, void* d_ws, size_t ws_size,
                              hipStream_t stream)
{
  const float* x   = (const float*)d_in[0];
  const int*   ei  = (const int*)d_in[1];
  const float* W1  = (const float*)d_in[2];
  const float* b1  = (const float*)d_in[3];
  const float* W2  = (const float*)d_in[4];
  const float* b2  = (const float*)d_in[5];
  const float* W3  = (const float*)d_in[6];
  const float* b3  = (const float*)d_in[7];
  const float* mw1 = (const float*)d_in[8];
  const float* mb1 = (const float*)d_in[9];
  const float* mw2 = (const float*)d_in[10];
  const float* mb2 = (const float*)d_in[11];
  const float* mw3 = (const float*)d_in[12];
  const float* mb3 = (const float*)d_in[13];
  const float* par = (const float*)d_in[14];
  const int* row = ei;
  const int* col = ei + EE;
  float* out = (float*)d_out;

  char* ws = (char*)d_ws;
  unsigned short* x_bf  = (unsigned short*)(ws + O_XBF);
  float*          h0    = (float*)(ws + O_XBF);            // reuse after gcn1 GEMM
  unsigned short* h1_bf = (unsigned short*)(ws + O_H1);
  unsigned short* g2_bf = (unsigned short*)(ws + O_H1);    // reuse (h1 dead)
  unsigned short* x2_bf = (unsigned short*)(ws + O_H1 + 25600000);
  unsigned short* g1_bf = (unsigned short*)(ws + O_G1);
  unsigned short* x1_bf = (unsigned short*)(ws + O_X1);
  unsigned short* h2_bf = (unsigned short*)(ws + O_H2);
  float* Lg      = (float*)(ws + O_LG);
  float* Tg      = (float*)(ws + O_TG);
  float* ew_raw  = (float*)(ws + O_EWR);
  float* y3      = (float*)(ws + O_EWR);                   // reuse (ew_raw dead)
  float* ew_std  = (float*)(ws + O_EWS);
  int*   csr_src = (int*)(ws + O_CSRS);
  double* part   = (double*)(ws + O_CSRS);                 // alias: dead before edge3 fills csr
  float* csr_w   = (float*)(ws + O_CSRW);
  unsigned short* mw1t = (unsigned short*)(ws + O_MW1T);
  unsigned short* w1t  = (unsigned short*)(ws + O_W1T);
  unsigned short* w2t  = (unsigned short*)(ws + O_W2T);
  unsigned short* mw2t = (unsigned short*)(ws + O_MW2T);
  float*  deg    = (float*)(ws + O_DEG);
  int*    cnt    = (int*)(ws + O_CNT);
  int*    cursor = (int*)(ws + O_CUR);
  double* red    = (double*)(ws + O_RED);
  int*    rowptr = (int*)(ws + O_RPT);
  float*  dinv   = (float*)(ws + O_DINV);

  // zero: deg, cnt, cursor (contiguous)
  hipMemsetAsync(ws + O_DEG, 0, 3 * 200192, stream);

  // fp32 -> bf16 conversions
  conv_f2bf4<<<25000, 256, 0, stream>>>(x, x_bf, NN * 512 / 4);
  conv_transpose<<<1024, 256, 0, stream>>>(mw1, mw1t, 512, 512);
  conv_transpose<<<512, 256, 0, stream>>>(W1, w1t, 512, 256);
  conv_transpose<<<256, 256, 0, stream>>>(W2, w2t, 256, 256);
  conv_transpose<<<128, 256, 0, stream>>>(mw2, mw2t, 512, 64);

  // pseudo-MLP
  gemm_bf16<true,  true ><<<dim3(391, 4), 256, 0, stream>>>(x_bf, 512, mw1t, mb1, h1_bf, 512, NN, 512, 512);
  gemm_bf16<true,  true ><<<dim3(391, 1), 256, 0, stream>>>(h1_bf, 512, mw2t, mb2, h2_bf, 64, NN, 64, 512);
  logits_kernel<<<196, 256, 0, stream>>>(h2_bf, mw3, mb3, par, Lg, Tg);

  // edge weights + CSR
  edge1_kernel<<<NB_EDGE, 256, 0, stream>>>(row, col, Lg, Tg, ew_raw, cnt, part);
  redpart_kernel<<<1, 1024, 0, stream>>>(part, red);
  edge2_kernel<<<NB_EDGE, 256, 0, stream>>>(ew_raw, col, red, ew_std, deg);
  dinv_kernel<<<196, 256, 0, stream>>>(deg, dinv);
  scan_kernel<<<1, 1024, 0, stream>>>(cnt, rowptr);
  edge3_kernel<<<NB_EDGE, 256, 0, stream>>>(row, col, ew_std, dinv, rowptr, cursor, csr_src, csr_w);

  // GCN layer 0
  gemm_bf16<false, false><<<dim3(391, 2), 256, 0, stream>>>(x_bf, 512, w1t, nullptr, g1_bf, 256, NN, 256, 512);
  agg256_kernel<0><<<12500, 256, 0, stream>>>(rowptr, csr_src, csr_w, g1_bf, dinv, b1, nullptr, h0, x1_bf);
  // GCN layer 1 (+residual h0)
  gemm_bf16<false, false><<<dim3(391, 2), 256, 0, stream>>>(x1_bf, 256, w2t, nullptr, g2_bf, 256, NN, 256, 256);
  agg256_kernel<1><<<12500, 256, 0, stream>>>(rowptr, csr_src, csr_w, g2_bf, dinv, b2, h0, nullptr, x2_bf);
  // GCN layer 2 (GEMM first, aggregate in dim 7)
  gemv7_kernel<<<196, 256, 0, stream>>>(x2_bf, W3, y3);
  agg7_kernel<<<1563, 256, 0, stream>>>(rowptr, csr_src, csr_w, y3, dinv, b3, out);
}

// Round 3
// 560.380 us; speedup vs baseline: 1.6007x; 1.1414x over previous
//
#include <hip/hip_runtime.h>

#define NN 50000
#define EE 800000
#define NB_EDGE 3125   // ceil(EE/256)

typedef __attribute__((ext_vector_type(4))) float f32x4;
typedef __attribute__((ext_vector_type(8))) short bf16x8;
typedef __attribute__((ext_vector_type(8))) unsigned short u16x8;

typedef const __attribute__((address_space(1))) void* gas_p;
typedef __attribute__((address_space(3))) void* las_p;

__device__ __forceinline__ float bf2f(unsigned short u) {
  union { unsigned int i; float f; } v; v.i = ((unsigned int)u) << 16; return v.f;
}
__device__ __forceinline__ unsigned short f2bf(float f) {
  union { float f; unsigned int i; } v; v.f = f;
  unsigned int u = v.i;
  return (unsigned short)((u + 0x7FFFu + ((u >> 16) & 1u)) >> 16);
}

// ---------------- workspace layout (bytes, all 256-aligned) ----------------
constexpr size_t O_XBF  = 0;                  // x_bf [50000,512]bf16; reused as h0 [50000,256]bf16
constexpr size_t O_H1   = O_XBF + 51200000;   // h1 [50000,512]bf16; reused: g2 (25.6MB) + x2 (25.6MB)
constexpr size_t O_G1   = O_H1  + 51200000;   // g1 [50000,256]bf16
constexpr size_t O_X1   = O_G1  + 25600000;   // x1 [50000,256]bf16
constexpr size_t O_H2   = O_X1  + 25600000;   // h2 [50000,64]bf16
constexpr size_t O_LG   = O_H2  + 6400000;    // Lg [50000,8]f32
constexpr size_t O_TG   = O_LG  + 1600000;    // Tg [50000,8]f32
constexpr size_t O_EWR  = O_TG  + 1600000;    // ew_raw [E]f32; reused as y3 [50000,8]f32
constexpr size_t O_EWS  = O_EWR + 3200000;    // ew_std [E]f32
constexpr size_t O_CSR  = O_EWS + 3200000;    // csr_sw [E]int2 (6.4MB; aliased: edge1 partials, dead by edge3)
constexpr size_t O_MW1T = O_CSR + 6400000;    // 512*512 bf16
constexpr size_t O_W1T  = O_MW1T + 524288;    // 256*512 bf16
constexpr size_t O_W2T  = O_W1T  + 262144;    // 256*256 bf16
constexpr size_t O_MW2T = O_W2T  + 131072;    // 64*512 bf16
constexpr size_t O_DEG  = O_MW2T + 65536;     // [N]f32   <- zero block start
constexpr size_t O_CNT  = O_DEG  + 200192;    // [N]i32
constexpr size_t O_CUR  = O_CNT  + 200192;    // [N]i32
constexpr size_t O_RED  = O_CUR  + 200192;    // 2 doubles <- zero block end
constexpr size_t O_RPT  = O_RED  + 256;       // [N+1]i32
constexpr size_t O_DINV = O_RPT  + 200192;    // [N]f32

// ---------------- conversions ----------------
__global__ __launch_bounds__(256) void conv_f2bf4(const float* __restrict__ in,
                                                  unsigned short* __restrict__ out, int n4) {
  int i = blockIdx.x * 256 + threadIdx.x;
  if (i >= n4) return;
  const float4 v = ((const float4*)in)[i];
  ushort4 o; o.x = f2bf(v.x); o.y = f2bf(v.y); o.z = f2bf(v.z); o.w = f2bf(v.w);
  ((ushort4*)out)[i] = o;
}

// all four weight transposes in one dispatch
__global__ __launch_bounds__(256)
void conv_weights(const float* __restrict__ mw1, const float* __restrict__ W1,
                  const float* __restrict__ W2, const float* __restrict__ mw2,
                  unsigned short* __restrict__ mw1t, unsigned short* __restrict__ w1t,
                  unsigned short* __restrict__ w2t, unsigned short* __restrict__ mw2t)
{
  int i = blockIdx.x * 256 + threadIdx.x;
  if (i < 262144) {                 // mw1: [512,512]
    int k = i >> 9, n = i & 511;
    mw1t[(size_t)n * 512 + k] = f2bf(mw1[i]);
  } else if (i < 393216) {          // W1: [512,256]
    int j = i - 262144, k = j >> 8, n = j & 255;
    w1t[(size_t)n * 512 + k] = f2bf(W1[j]);
  } else if (i < 458752) {          // W2: [256,256]
    int j = i - 393216, k = j >> 8, n = j & 255;
    w2t[(size_t)n * 256 + k] = f2bf(W2[j]);
  } else if (i < 491520) {          // mw2: [512,64]
    int j = i - 458752, k = j >> 6, n = j & 63;
    mw2t[(size_t)n * 512 + k] = f2bf(mw2[j]);
  }
}

// ---------------- bf16 MFMA GEMM: C[M,ldc] = A[M,lda] * Bt[N,K]^T ----------------
// grid: (col_tiles, row_tiles) -- col fastest so consecutive blocks share the A panel
template<bool RELU, bool BIAS>
__global__ __launch_bounds__(256)
void gemm_bf16(const unsigned short* __restrict__ A, int lda,
               const unsigned short* __restrict__ Bt,
               const float* __restrict__ bias,
               unsigned short* __restrict__ C, int ldc,
               int M, int N, int K)
{
  __shared__ unsigned short ldsA[128 * 32];
  __shared__ unsigned short ldsB[128 * 32];
  const int tid  = threadIdx.x;
  const int lane = tid & 63;
  const int wid  = tid >> 6;
  const int wm   = (wid >> 1) << 6;
  const int wn   = (wid & 1) << 6;
  const int bm   = blockIdx.y << 7;
  const int bn   = blockIdx.x << 7;

  f32x4 acc[4][4] = {};

  const int srow  = lane >> 2;
  const int sslot = lane & 3;

  for (int k0 = 0; k0 < K; k0 += 32) {
    if (k0) __syncthreads();
#pragma unroll
    for (int c = 0; c < 2; ++c) {
      const int chunk = c * 4 + wid;
      const int row   = chunk * 16 + srow;
      const int ks    = sslot ^ ((row >> 1) & 3);
      int ga = bm + row; ga = ga < M ? ga : M - 1;
      int gb = bn + row; gb = gb < N ? gb : N - 1;
      const char* srcA = (const char*)A  + ((size_t)ga * lda + k0) * 2 + ks * 16;
      const char* srcB = (const char*)Bt + ((size_t)gb * K   + k0) * 2 + ks * 16;
      __builtin_amdgcn_global_load_lds((gas_p)srcA, (las_p)(ldsA + chunk * 512), 16, 0, 0);
      __builtin_amdgcn_global_load_lds((gas_p)srcB, (las_p)(ldsB + chunk * 512), 16, 0, 0);
    }
    __syncthreads();

    const int q   = lane >> 4;
    const int r15 = lane & 15;
    bf16x8 af[4], bfr[4];
#pragma unroll
    for (int m = 0; m < 4; ++m) {
      const int ra = wm + m * 16 + r15;
      af[m]  = *(const bf16x8*)(ldsA + ra * 32 + (q ^ ((ra >> 1) & 3)) * 8);
      const int rb = wn + m * 16 + r15;
      bfr[m] = *(const bf16x8*)(ldsB + rb * 32 + (q ^ ((rb >> 1) & 3)) * 8);
    }
#pragma unroll
    for (int m = 0; m < 4; ++m)
#pragma unroll
      for (int n = 0; n < 4; ++n)
        acc[m][n] = __builtin_amdgcn_mfma_f32_16x16x32_bf16(af[m], bfr[n], acc[m][n], 0, 0, 0);
  }

  const int q   = lane >> 4;
  const int r15 = lane & 15;
#pragma unroll
  for (int m = 0; m < 4; ++m) {
#pragma unroll
    for (int n = 0; n < 4; ++n) {
      const int gc = bn + wn + n * 16 + r15;
#pragma unroll
      for (int i = 0; i < 4; ++i) {
        const int gr = bm + wm + m * 16 + q * 4 + i;
        if (gr < M && gc < N) {
          float f = acc[m][n][i];
          if (BIAS) f += bias[gc];
          if (RELU) f = fmaxf(f, 0.f);
          C[(size_t)gr * ldc + gc] = f2bf(f);
        }
      }
    }
  }
}

// ---------------- logits (h2[N,64] @ mw3[64,7] + mb3) and T = L @ relu(2*P) ----------------
__global__ __launch_bounds__(256)
void logits_kernel(const unsigned short* __restrict__ h2, const float* __restrict__ mw3,
                   const float* __restrict__ mb3, const float* __restrict__ par,
                   float* __restrict__ Lg, float* __restrict__ Tg)
{
  __shared__ float w[64 * 8];
  __shared__ float P[64];
  int tid = threadIdx.x;
  for (int i = tid; i < 512; i += 256) {
    int k = i >> 3, c = i & 7;
    w[i] = (c < 7) ? mw3[k * 7 + c] : 0.f;
  }
  if (tid < 64) {
    int d = tid >> 3, c = tid & 7;
    P[tid] = (d < 7 && c < 7) ? fmaxf(2.0f * par[d * 7 + c], 0.f) : 0.f;
  }
  __syncthreads();
  int n = blockIdx.x * 256 + tid;
  if (n >= NN) return;
  const unsigned short* hr = h2 + (size_t)n * 64;
  f32x4 L0 = {0,0,0,0}, L1 = {0,0,0,0};
  for (int k = 0; k < 64; k += 4) {
    ushort4 v = *(const ushort4*)(hr + k);
    float xs[4] = {bf2f(v.x), bf2f(v.y), bf2f(v.z), bf2f(v.w)};
#pragma unroll
    for (int j = 0; j < 4; ++j) {
      L0 += xs[j] * *(const f32x4*)&w[(k + j) * 8];
      L1 += xs[j] * *(const f32x4*)&w[(k + j) * 8 + 4];
    }
  }
  float Ls[8] = {L0[0], L0[1], L0[2], L0[3], L1[0], L1[1], L1[2], 0.f};
#pragma unroll
  for (int c = 0; c < 7; ++c) Ls[c] += mb3[c];
  f32x4 T0 = {0,0,0,0}, T1 = {0,0,0,0};
#pragma unroll
  for (int d = 0; d < 7; ++d) {
    T0 += Ls[d] * *(const f32x4*)&P[d * 8];
    T1 += Ls[d] * *(const f32x4*)&P[d * 8 + 4];
  }
  f32x4 o0 = {Ls[0], Ls[1], Ls[2], Ls[3]};
  f32x4 o1 = {Ls[4], Ls[5], Ls[6], 0.f};
  *(f32x4*)(Lg + (size_t)n * 8)     = o0;
  *(f32x4*)(Lg + (size_t)n * 8 + 4) = o1;
  *(f32x4*)(Tg + (size_t)n * 8)     = T0;
  *(f32x4*)(Tg + (size_t)n * 8 + 4) = T1;
}

// ---------------- edge pass 1: raw ew, dest histogram, per-block sum/sumsq partials ----------------
__global__ __launch_bounds__(256)
void edge1_kernel(const int* __restrict__ row, const int* __restrict__ col,
                  const float* __restrict__ Lg, const float* __restrict__ Tg,
                  float* __restrict__ ew_raw, int* __restrict__ cnt,
                  double* __restrict__ part)
{
  __shared__ double shs[4], shs2[4];
  int e = blockIdx.x * 256 + threadIdx.x;
  double s = 0.0, s2 = 0.0;
  if (e < EE) {
    int r = row[e], c = col[e];
    float4 a0 = *(const float4*)(Lg + (size_t)r * 8);
    float4 a1 = *(const float4*)(Lg + (size_t)r * 8 + 4);
    float4 b0 = *(const float4*)(Tg + (size_t)c * 8);
    float4 b1 = *(const float4*)(Tg + (size_t)c * 8 + 4);
    float v = a0.x*b0.x + a0.y*b0.y + a0.z*b0.z + a0.w*b0.w
            + a1.x*b1.x + a1.y*b1.y + a1.z*b1.z + a1.w*b1.w;
    ew_raw[e] = v;
    atomicAdd(&cnt[c], 1);
    s = (double)v; s2 = (double)v * (double)v;
  }
  for (int off = 32; off; off >>= 1) {
    s  += __shfl_down(s, off);
    s2 += __shfl_down(s2, off);
  }
  int wv = threadIdx.x >> 6;
  if ((threadIdx.x & 63) == 0) { shs[wv] = s; shs2[wv] = s2; }
  __syncthreads();
  if (threadIdx.x == 0) {
    part[blockIdx.x]           = shs[0] + shs[1] + shs[2] + shs[3];
    part[NB_EDGE + blockIdx.x] = shs2[0] + shs2[1] + shs2[2] + shs2[3];
  }
}

// ---------------- reduce edge1 partials -> red ----------------
__global__ __launch_bounds__(1024)
void redpart_kernel(const double* __restrict__ part, double* __restrict__ red)
{
  __shared__ double sh[16][2];
  int tid = threadIdx.x;
  double s = 0.0, s2 = 0.0;
  for (int i = tid; i < NB_EDGE; i += 1024) {
    s  += part[i];
    s2 += part[NB_EDGE + i];
  }
  for (int off = 32; off; off >>= 1) {
    s  += __shfl_down(s, off);
    s2 += __shfl_down(s2, off);
  }
  if ((tid & 63) == 0) { sh[tid >> 6][0] = s; sh[tid >> 6][1] = s2; }
  __syncthreads();
  if (tid == 0) {
    double a = 0.0, b = 0.0;
    for (int i = 0; i < 16; ++i) { a += sh[i][0]; b += sh[i][1]; }
    red[0] = a; red[1] = b;
  }
}

// ---------------- edge pass 2: standardize, accumulate deg ----------------
__global__ __launch_bounds__(256)
void edge2_kernel(const float* __restrict__ ew_raw, const int* __restrict__ col,
                  const double* __restrict__ red,
                  float* __restrict__ ew_std, float* __restrict__ deg)
{
  int e = blockIdx.x * 256 + threadIdx.x;
  if (e >= EE) return;
  double mean = red[0] / (double)EE;
  double var  = (red[1] - (double)EE * mean * mean) / (double)(EE - 1);
  double scl  = sqrt(1e-4 / var);
  float v = (float)(((double)ew_raw[e] - mean) * scl) + 1.0f;
  ew_std[e] = v;
  atomicAdd(&deg[col[e]], v);
}

__global__ __launch_bounds__(256)
void dinv_kernel(const float* __restrict__ deg, float* __restrict__ dinv)
{
  int n = blockIdx.x * 256 + threadIdx.x;
  if (n >= NN) return;
  float d = deg[n] + 1.0f;
  dinv[n] = d > 0.f ? 1.0f / sqrtf(fmaxf(d, 1e-12f)) : 0.f;
}

// ---------------- exclusive scan of cnt -> rowptr (single block) ----------------
__global__ __launch_bounds__(1024)
void scan_kernel(const int* __restrict__ cnt, int* __restrict__ rowptr)
{
  constexpr int CH = 49;
  __shared__ int sh[1024];
  int tid  = threadIdx.x;
  int base = tid * CH;
  int sum = 0;
  for (int i = 0; i < CH; ++i) {
    int idx = base + i;
    if (idx < NN) sum += cnt[idx];
  }
  sh[tid] = sum;
  __syncthreads();
  for (int off = 1; off < 1024; off <<= 1) {
    int t = (tid >= off) ? sh[tid - off] : 0;
    __syncthreads();
    sh[tid] += t;
    __syncthreads();
  }
  int run = (tid > 0) ? sh[tid - 1] : 0;
  if (tid == 0) rowptr[0] = 0;
  for (int i = 0; i < CH; ++i) {
    int idx = base + i;
    if (idx < NN) { run += cnt[idx]; rowptr[idx + 1] = run; }
  }
}

// ---------------- edge pass 3: fill CSR (by destination), fused (src, w) ----------------
__global__ __launch_bounds__(256)
void edge3_kernel(const int* __restrict__ row, const int* __restrict__ col,
                  const float* __restrict__ ew_std, const float* __restrict__ dinv,
                  const int* __restrict__ rowptr, int* __restrict__ cursor,
                  int2* __restrict__ csr_sw)
{
  int e = blockIdx.x * 256 + threadIdx.x;
  if (e >= EE) return;
  int r = row[e], c = col[e];
  float w = dinv[r] * ew_std[e] * dinv[c];
  int pos = atomicAdd(&cursor[c], 1);
  int2 sw; sw.x = r; sw.y = __float_as_int(w);
  csr_sw[rowptr[c] + pos] = sw;
}

// ---------------- dim-256 aggregation: one wave per node, half-wave edge split ----------------
// MODE 0: h0 = bf16(agg(g1)+b), x1 = bf16(relu(agg+b))
// MODE 1: x2 = bf16(relu(agg(g2)+b) + h0)
template<int MODE>
__global__ __launch_bounds__(256)
void agg256_kernel(const int* __restrict__ rowptr, const int2* __restrict__ csr_sw,
                   const unsigned short* __restrict__ gsrc,
                   const float* __restrict__ dinv, const float* __restrict__ bias,
                   const unsigned short* __restrict__ h0in,
                   unsigned short* __restrict__ h0out,
                   unsigned short* __restrict__ xout)
{
  int n = blockIdx.x * 4 + (threadIdx.x >> 6);
  if (n >= NN) return;
  const int lane = threadIdx.x & 63;
  const int half = lane >> 5;
  const int l5   = lane & 31;
  const size_t colbase = (size_t)(l5 << 3);   // 8 dims per lane during accumulation

  float a0=0,a1=0,a2=0,a3=0,a4=0,a5=0,a6=0,a7=0;
  const int s = rowptr[n], e = rowptr[n + 1];
  int i = s + half;
  for (; i + 2 < e; i += 4) {                 // two edges per half-wave per iter
    int2 sw0 = csr_sw[i];
    int2 sw1 = csr_sw[i + 2];
    u16x8 v0 = *(const u16x8*)(gsrc + (size_t)sw0.x * 256 + colbase);
    u16x8 v1 = *(const u16x8*)(gsrc + (size_t)sw1.x * 256 + colbase);
    float w0 = __int_as_float(sw0.y);
    float w1 = __int_as_float(sw1.y);
    a0 += w0 * bf2f(v0[0]); a1 += w0 * bf2f(v0[1]);
    a2 += w0 * bf2f(v0[2]); a3 += w0 * bf2f(v0[3]);
    a4 += w0 * bf2f(v0[4]); a5 += w0 * bf2f(v0[5]);
    a6 += w0 * bf2f(v0[6]); a7 += w0 * bf2f(v0[7]);
    a0 += w1 * bf2f(v1[0]); a1 += w1 * bf2f(v1[1]);
    a2 += w1 * bf2f(v1[2]); a3 += w1 * bf2f(v1[3]);
    a4 += w1 * bf2f(v1[4]); a5 += w1 * bf2f(v1[5]);
    a6 += w1 * bf2f(v1[6]); a7 += w1 * bf2f(v1[7]);
  }
  if (i < e) {
    int2 sw = csr_sw[i];
    u16x8 v = *(const u16x8*)(gsrc + (size_t)sw.x * 256 + colbase);
    float w = __int_as_float(sw.y);
    a0 += w * bf2f(v[0]); a1 += w * bf2f(v[1]);
    a2 += w * bf2f(v[2]); a3 += w * bf2f(v[3]);
    a4 += w * bf2f(v[4]); a5 += w * bf2f(v[5]);
    a6 += w * bf2f(v[6]); a7 += w * bf2f(v[7]);
  }
  // combine the two halves
  a0 += __shfl_xor(a0, 32); a1 += __shfl_xor(a1, 32);
  a2 += __shfl_xor(a2, 32); a3 += __shfl_xor(a3, 32);
  a4 += __shfl_xor(a4, 32); a5 += __shfl_xor(a5, 32);
  a6 += __shfl_xor(a6, 32); a7 += __shfl_xor(a7, 32);
  // this lane's final 4 dims
  float f0 = half ? a4 : a0;
  float f1 = half ? a5 : a1;
  float f2 = half ? a6 : a2;
  float f3 = half ? a7 : a3;
  const int dbase = (l5 << 3) + (half << 2);
  // self-loop
  float wd = dinv[n]; wd *= wd;
  ushort4 sv = *(const ushort4*)(gsrc + (size_t)n * 256 + dbase);
  f0 += wd * bf2f(sv.x); f1 += wd * bf2f(sv.y);
  f2 += wd * bf2f(sv.z); f3 += wd * bf2f(sv.w);
  float4 b = *(const float4*)(bias + dbase);
  f0 += b.x; f1 += b.y; f2 += b.z; f3 += b.w;
  const size_t o = (size_t)n * 256 + dbase;
  if (MODE == 0) {
    ushort4 h;
    h.x = f2bf(f0); h.y = f2bf(f1); h.z = f2bf(f2); h.w = f2bf(f3);
    *(ushort4*)(h0out + o) = h;
    ushort4 xo;
    xo.x = f2bf(fmaxf(f0, 0.f)); xo.y = f2bf(fmaxf(f1, 0.f));
    xo.z = f2bf(fmaxf(f2, 0.f)); xo.w = f2bf(fmaxf(f3, 0.f));
    *(ushort4*)(xout + o) = xo;
  } else {
    ushort4 h = *(const ushort4*)(h0in + o);
    ushort4 xo;
    xo.x = f2bf(fmaxf(f0, 0.f) + bf2f(h.x));
    xo.y = f2bf(fmaxf(f1, 0.f) + bf2f(h.y));
    xo.z = f2bf(fmaxf(f2, 0.f) + bf2f(h.z));
    xo.w = f2bf(fmaxf(f3, 0.f) + bf2f(h.w));
    *(ushort4*)(xout + o) = xo;
  }
}

// ---------------- y3[N,8] = x2[N,256] @ W3[256,7] ----------------
__global__ __launch_bounds__(256)
void gemv7_kernel(const unsigned short* __restrict__ x2, const float* __restrict__ W3,
                  float* __restrict__ y3)
{
  __shared__ float w[256 * 8];
  int tid = threadIdx.x;
  for (int i = tid; i < 2048; i += 256) {
    int k = i >> 3, c = i & 7;
    w[i] = (c < 7) ? W3[k * 7 + c] : 0.f;
  }
  __syncthreads();
  int n = blockIdx.x * 256 + tid;
  if (n >= NN) return;
  const unsigned short* xr = x2 + (size_t)n * 256;
  f32x4 accLo = {0,0,0,0}, accHi = {0,0,0,0};
  for (int k = 0; k < 256; k += 4) {
    ushort4 v = *(const ushort4*)(xr + k);
    float xs[4] = {bf2f(v.x), bf2f(v.y), bf2f(v.z), bf2f(v.w)};
#pragma unroll
    for (int j = 0; j < 4; ++j) {
      accLo += xs[j] * *(const f32x4*)&w[(k + j) * 8];
      accHi += xs[j] * *(const f32x4*)&w[(k + j) * 8 + 4];
    }
  }
  *(f32x4*)(y3 + (size_t)n * 8)     = accLo;
  *(f32x4*)(y3 + (size_t)n * 8 + 4) = accHi;
}

// ---------------- dim-7 aggregation: 8 lanes per node ----------------
__global__ __launch_bounds__(256)
void agg7_kernel(const int* __restrict__ rowptr, const int2* __restrict__ csr_sw,
                 const float* __restrict__ y3,
                 const float* __restrict__ dinv, const float* __restrict__ b3,
                 float* __restrict__ out)
{
  int n = blockIdx.x * 32 + (threadIdx.x >> 3);
  if (n >= NN) return;
  int j = threadIdx.x & 7;
  float acc = 0.f;
  int s = rowptr[n], e = rowptr[n + 1];
  for (int i = s; i < e; ++i) {
    int2 sw = csr_sw[i];
    acc += __int_as_float(sw.y) * y3[(size_t)sw.x * 8 + j];
  }
  float wd = dinv[n]; wd *= wd;
  acc += wd * y3[(size_t)n * 8 + j];
  if (j < 7) out[(size_t)n * 7 + j] = acc + b3[j];
}

// ---------------- host ----------------
extern "C" void kernel_launch(void* const* d_in, const int* in_sizes, int n_in,
                              void* d_out, int out_size, void* d_ws, size_t ws_size,
                              hipStream_t stream)
{
  const float* x   = (const float*)d_in[0];
  const int*   ei  = (const int*)d_in[1];
  const float* W1  = (const float*)d_in[2];
  const float* b1  = (const float*)d_in[3];
  const float* W2  = (const float*)d_in[4];
  const float* b2  = (const float*)d_in[5];
  const float* W3  = (const float*)d_in[6];
  const float* b3  = (const float*)d_in[7];
  const float* mw1 = (const float*)d_in[8];
  const float* mb1 = (const float*)d_in[9];
  const float* mw2 = (const float*)d_in[10];
  const float* mb2 = (const float*)d_in[11];
  const float* mw3 = (const float*)d_in[12];
  const float* mb3 = (const float*)d_in[13];
  const float* par = (const float*)d_in[14];
  const int* row = ei;
  const int* col = ei + EE;
  float* out = (float*)d_out;

  char* ws = (char*)d_ws;
  unsigned short* x_bf  = (unsigned short*)(ws + O_XBF);
  unsigned short* h0    = (unsigned short*)(ws + O_XBF);   // bf16, alias (x_bf dead after gcn1 GEMM)
  unsigned short* h1_bf = (unsigned short*)(ws + O_H1);
  unsigned short* g2_bf = (unsigned short*)(ws + O_H1);    // reuse (h1 dead)
  unsigned short* x2_bf = (unsigned short*)(ws + O_H1 + 25600000);
  unsigned short* g1_bf = (unsigned short*)(ws + O_G1);
  unsigned short* x1_bf = (unsigned short*)(ws + O_X1);
  unsigned short* h2_bf = (unsigned short*)(ws + O_H2);
  float* Lg      = (float*)(ws + O_LG);
  float* Tg      = (float*)(ws + O_TG);
  float* ew_raw  = (float*)(ws + O_EWR);
  float* y3      = (float*)(ws + O_EWR);                   // reuse (ew_raw dead)
  float* ew_std  = (float*)(ws + O_EWS);
  int2*  csr_sw  = (int2*)(ws + O_CSR);
  double* part   = (double*)(ws + O_CSR);                  // alias: dead before edge3
  unsigned short* mw1t = (unsigned short*)(ws + O_MW1T);
  unsigned short* w1t  = (unsigned short*)(ws + O_W1T);
  unsigned short* w2t  = (unsigned short*)(ws + O_W2T);
  unsigned short* mw2t = (unsigned short*)(ws + O_MW2T);
  float*  deg    = (float*)(ws + O_DEG);
  int*    cnt    = (int*)(ws + O_CNT);
  int*    cursor = (int*)(ws + O_CUR);
  double* red    = (double*)(ws + O_RED);
  int*    rowptr = (int*)(ws + O_RPT);
  float*  dinv   = (float*)(ws + O_DINV);

  // zero: deg, cnt, cursor (contiguous)
  hipMemsetAsync(ws + O_DEG, 0, 3 * 200192, stream);

  // fp32 -> bf16 conversions
  conv_f2bf4<<<25000, 256, 0, stream>>>(x, x_bf, NN * 512 / 4);
  conv_weights<<<1920, 256, 0, stream>>>(mw1, W1, W2, mw2, mw1t, w1t, w2t, mw2t);

  // pseudo-MLP
  gemm_bf16<true,  true ><<<dim3(4, 391), 256, 0, stream>>>(x_bf, 512, mw1t, mb1, h1_bf, 512, NN, 512, 512);
  gemm_bf16<true,  true ><<<dim3(1, 391), 256, 0, stream>>>(h1_bf, 512, mw2t, mb2, h2_bf, 64, NN, 64, 512);
  logits_kernel<<<196, 256, 0, stream>>>(h2_bf, mw3, mb3, par, Lg, Tg);

  // edge weights + CSR
  edge1_kernel<<<NB_EDGE, 256, 0, stream>>>(row, col, Lg, Tg, ew_raw, cnt, part);
  redpart_kernel<<<1, 1024, 0, stream>>>(part, red);
  edge2_kernel<<<NB_EDGE, 256, 0, stream>>>(ew_raw, col, red, ew_std, deg);
  dinv_kernel<<<196, 256, 0, stream>>>(deg, dinv);
  scan_kernel<<<1, 1024, 0, stream>>>(cnt, rowptr);
  edge3_kernel<<<NB_EDGE, 256, 0, stream>>>(row, col, ew_std, dinv, rowptr, cursor, csr_sw);

  // GCN layer 0
  gemm_bf16<false, false><<<dim3(2, 391), 256, 0, stream>>>(x_bf, 512, w1t, nullptr, g1_bf, 256, NN, 256, 512);
  agg256_kernel<0><<<12500, 256, 0, stream>>>(rowptr, csr_sw, g1_bf, dinv, b1, nullptr, h0, x1_bf);
  // GCN layer 1 (+residual h0)
  gemm_bf16<false, false><<<dim3(2, 391), 256, 0, stream>>>(x1_bf, 256, w2t, nullptr, g2_bf, 256, NN, 256, 256);
  agg256_kernel<1><<<12500, 256, 0, stream>>>(rowptr, csr_sw, g2_bf, dinv, b2, h0, nullptr, x2_bf);
  // GCN layer 2 (GEMM first, aggregate in dim 7)
  gemv7_kernel<<<196, 256, 0, stream>>>(x2_bf, W3, y3);
  agg7_kernel<<<1563, 256, 0, stream>>>(rowptr, csr_sw, y3, dinv, b3, out);
}

// Round 4
// 478.315 us; speedup vs baseline: 1.8753x; 1.1716x over previous
//
#include <hip/hip_runtime.h>

#define NN 50000
#define EE 800000
#define NB_EDGE 3125   // ceil(EE/256)
#define NB_SCAN 196    // ceil(NN/256)

typedef __attribute__((ext_vector_type(4))) float f32x4;
typedef __attribute__((ext_vector_type(8))) short bf16x8;
typedef __attribute__((ext_vector_type(8))) unsigned short u16x8;

typedef const __attribute__((address_space(1))) void* gas_p;
typedef __attribute__((address_space(3))) void* las_p;

__device__ __forceinline__ float bf2f(unsigned short u) {
  union { unsigned int i; float f; } v; v.i = ((unsigned int)u) << 16; return v.f;
}
__device__ __forceinline__ unsigned short f2bf(float f) {
  union { float f; unsigned int i; } v; v.f = f;
  unsigned int u = v.i;
  return (unsigned short)((u + 0x7FFFu + ((u >> 16) & 1u)) >> 16);
}

// ---------------- workspace layout (bytes, all 256-aligned) ----------------
constexpr size_t O_XBF  = 0;                  // x_bf [50000,512]bf16; reused as h0 [50000,256]bf16
constexpr size_t O_H1   = O_XBF + 51200000;   // h1 [50000,512]bf16; reused: g2 (25.6MB) + x2 (25.6MB)
constexpr size_t O_G1   = O_H1  + 51200000;   // g1 [50000,256]bf16
constexpr size_t O_X1   = O_G1  + 25600000;   // x1 [50000,256]bf16
constexpr size_t O_H2   = O_X1  + 25600000;   // h2 [50000,64]bf16
constexpr size_t O_LG   = O_H2  + 6400000;    // Lg [50000,8]f32
constexpr size_t O_TG   = O_LG  + 1600000;    // Tg [50000,8]f32
constexpr size_t O_EWR  = O_TG  + 1600000;    // ew_raw [E]f32; reused as y3 [50000,8]f32
constexpr size_t O_EWS  = O_EWR + 3200000;    // ew_std [E]f32
constexpr size_t O_CSR  = O_EWS + 3200000;    // csr_sw [E]int2 (6.4MB; aliased: edge1 partials, dead by edge3)
constexpr size_t O_MW1T = O_CSR + 6400000;    // 512*512 bf16
constexpr size_t O_W1T  = O_MW1T + 524288;    // 256*512 bf16
constexpr size_t O_W2T  = O_W1T  + 262144;    // 256*256 bf16
constexpr size_t O_MW2T = O_W2T  + 131072;    // 64*512 bf16
constexpr size_t O_DEG  = O_MW2T + 65536;     // [N]f32   <- zero block start
constexpr size_t O_CNT  = O_DEG  + 200192;    // [N]i32
constexpr size_t O_CUR  = O_CNT  + 200192;    // [N]i32
constexpr size_t O_RED  = O_CUR  + 200192;    // 2 doubles <- zero block end
constexpr size_t O_RPT  = O_RED  + 256;       // [N+1]i32
constexpr size_t O_DINV = O_RPT  + 200192;    // [N]f32
constexpr size_t O_BSUM = O_DINV + 200192;    // [NB_SCAN]i32 block sums

// ---------------- conversions ----------------
__global__ __launch_bounds__(256) void conv_f2bf4(const float* __restrict__ in,
                                                  unsigned short* __restrict__ out, int n4) {
  int i = blockIdx.x * 256 + threadIdx.x;
  if (i >= n4) return;
  const float4 v = ((const float4*)in)[i];
  ushort4 o; o.x = f2bf(v.x); o.y = f2bf(v.y); o.z = f2bf(v.z); o.w = f2bf(v.w);
  ((ushort4*)out)[i] = o;
}

// all four weight transposes in one dispatch
__global__ __launch_bounds__(256)
void conv_weights(const float* __restrict__ mw1, const float* __restrict__ W1,
                  const float* __restrict__ W2, const float* __restrict__ mw2,
                  unsigned short* __restrict__ mw1t, unsigned short* __restrict__ w1t,
                  unsigned short* __restrict__ w2t, unsigned short* __restrict__ mw2t)
{
  int i = blockIdx.x * 256 + threadIdx.x;
  if (i < 262144) {                 // mw1: [512,512]
    int k = i >> 9, n = i & 511;
    mw1t[(size_t)n * 512 + k] = f2bf(mw1[i]);
  } else if (i < 393216) {          // W1: [512,256]
    int j = i - 262144, k = j >> 8, n = j & 255;
    w1t[(size_t)n * 512 + k] = f2bf(W1[j]);
  } else if (i < 458752) {          // W2: [256,256]
    int j = i - 393216, k = j >> 8, n = j & 255;
    w2t[(size_t)n * 256 + k] = f2bf(W2[j]);
  } else if (i < 491520) {          // mw2: [512,64]
    int j = i - 458752, k = j >> 6, n = j & 63;
    mw2t[(size_t)n * 512 + k] = f2bf(mw2[j]);
  }
}

// ---------------- bf16 MFMA GEMM: C[M,ldc] = A[M,lda] * Bt[N,K]^T ----------------
template<bool RELU, bool BIAS>
__global__ __launch_bounds__(256)
void gemm_bf16(const unsigned short* __restrict__ A, int lda,
               const unsigned short* __restrict__ Bt,
               const float* __restrict__ bias,
               unsigned short* __restrict__ C, int ldc,
               int M, int N, int K)
{
  __shared__ unsigned short ldsA[128 * 32];
  __shared__ unsigned short ldsB[128 * 32];
  const int tid  = threadIdx.x;
  const int lane = tid & 63;
  const int wid  = tid >> 6;
  const int wm   = (wid >> 1) << 6;
  const int wn   = (wid & 1) << 6;
  const int bm   = blockIdx.y << 7;
  const int bn   = blockIdx.x << 7;

  f32x4 acc[4][4] = {};

  const int srow  = lane >> 2;
  const int sslot = lane & 3;

  for (int k0 = 0; k0 < K; k0 += 32) {
    if (k0) __syncthreads();
#pragma unroll
    for (int c = 0; c < 2; ++c) {
      const int chunk = c * 4 + wid;
      const int row   = chunk * 16 + srow;
      const int ks    = sslot ^ ((row >> 1) & 3);
      int ga = bm + row; ga = ga < M ? ga : M - 1;
      int gb = bn + row; gb = gb < N ? gb : N - 1;
      const char* srcA = (const char*)A  + ((size_t)ga * lda + k0) * 2 + ks * 16;
      const char* srcB = (const char*)Bt + ((size_t)gb * K   + k0) * 2 + ks * 16;
      __builtin_amdgcn_global_load_lds((gas_p)srcA, (las_p)(ldsA + chunk * 512), 16, 0, 0);
      __builtin_amdgcn_global_load_lds((gas_p)srcB, (las_p)(ldsB + chunk * 512), 16, 0, 0);
    }
    __syncthreads();

    const int q   = lane >> 4;
    const int r15 = lane & 15;
    bf16x8 af[4], bfr[4];
#pragma unroll
    for (int m = 0; m < 4; ++m) {
      const int ra = wm + m * 16 + r15;
      af[m]  = *(const bf16x8*)(ldsA + ra * 32 + (q ^ ((ra >> 1) & 3)) * 8);
      const int rb = wn + m * 16 + r15;
      bfr[m] = *(const bf16x8*)(ldsB + rb * 32 + (q ^ ((rb >> 1) & 3)) * 8);
    }
#pragma unroll
    for (int m = 0; m < 4; ++m)
#pragma unroll
      for (int n = 0; n < 4; ++n)
        acc[m][n] = __builtin_amdgcn_mfma_f32_16x16x32_bf16(af[m], bfr[n], acc[m][n], 0, 0, 0);
  }

  const int q   = lane >> 4;
  const int r15 = lane & 15;
#pragma unroll
  for (int m = 0; m < 4; ++m) {
#pragma unroll
    for (int n = 0; n < 4; ++n) {
      const int gc = bn + wn + n * 16 + r15;
#pragma unroll
      for (int i = 0; i < 4; ++i) {
        const int gr = bm + wm + m * 16 + q * 4 + i;
        if (gr < M && gc < N) {
          float f = acc[m][n][i];
          if (BIAS) f += bias[gc];
          if (RELU) f = fmaxf(f, 0.f);
          C[(size_t)gr * ldc + gc] = f2bf(f);
        }
      }
    }
  }
}

// ---------------- logits (h2[N,64] @ mw3[64,7] + mb3) and T = L @ relu(2*P) ----------------
__global__ __launch_bounds__(256)
void logits_kernel(const unsigned short* __restrict__ h2, const float* __restrict__ mw3,
                   const float* __restrict__ mb3, const float* __restrict__ par,
                   float* __restrict__ Lg, float* __restrict__ Tg)
{
  __shared__ float w[64 * 8];
  __shared__ float P[64];
  int tid = threadIdx.x;
  for (int i = tid; i < 512; i += 256) {
    int k = i >> 3, c = i & 7;
    w[i] = (c < 7) ? mw3[k * 7 + c] : 0.f;
  }
  if (tid < 64) {
    int d = tid >> 3, c = tid & 7;
    P[tid] = (d < 7 && c < 7) ? fmaxf(2.0f * par[d * 7 + c], 0.f) : 0.f;
  }
  __syncthreads();
  int n = blockIdx.x * 256 + tid;
  if (n >= NN) return;
  const unsigned short* hr = h2 + (size_t)n * 64;
  f32x4 L0 = {0,0,0,0}, L1 = {0,0,0,0};
  for (int k = 0; k < 64; k += 4) {
    ushort4 v = *(const ushort4*)(hr + k);
    float xs[4] = {bf2f(v.x), bf2f(v.y), bf2f(v.z), bf2f(v.w)};
#pragma unroll
    for (int j = 0; j < 4; ++j) {
      L0 += xs[j] * *(const f32x4*)&w[(k + j) * 8];
      L1 += xs[j] * *(const f32x4*)&w[(k + j) * 8 + 4];
    }
  }
  float Ls[8] = {L0[0], L0[1], L0[2], L0[3], L1[0], L1[1], L1[2], 0.f};
#pragma unroll
  for (int c = 0; c < 7; ++c) Ls[c] += mb3[c];
  f32x4 T0 = {0,0,0,0}, T1 = {0,0,0,0};
#pragma unroll
  for (int d = 0; d < 7; ++d) {
    T0 += Ls[d] * *(const f32x4*)&P[d * 8];
    T1 += Ls[d] * *(const f32x4*)&P[d * 8 + 4];
  }
  f32x4 o0 = {Ls[0], Ls[1], Ls[2], Ls[3]};
  f32x4 o1 = {Ls[4], Ls[5], Ls[6], 0.f};
  *(f32x4*)(Lg + (size_t)n * 8)     = o0;
  *(f32x4*)(Lg + (size_t)n * 8 + 4) = o1;
  *(f32x4*)(Tg + (size_t)n * 8)     = T0;
  *(f32x4*)(Tg + (size_t)n * 8 + 4) = T1;
}

// ---------------- edge pass 1: raw ew, dest histogram, per-block sum/sumsq partials ----------------
__global__ __launch_bounds__(256)
void edge1_kernel(const int* __restrict__ row, const int* __restrict__ col,
                  const float* __restrict__ Lg, const float* __restrict__ Tg,
                  float* __restrict__ ew_raw, int* __restrict__ cnt,
                  double* __restrict__ part)
{
  __shared__ double shs[4], shs2[4];
  int e = blockIdx.x * 256 + threadIdx.x;
  double s = 0.0, s2 = 0.0;
  if (e < EE) {
    int r = row[e], c = col[e];
    float4 a0 = *(const float4*)(Lg + (size_t)r * 8);
    float4 a1 = *(const float4*)(Lg + (size_t)r * 8 + 4);
    float4 b0 = *(const float4*)(Tg + (size_t)c * 8);
    float4 b1 = *(const float4*)(Tg + (size_t)c * 8 + 4);
    float v = a0.x*b0.x + a0.y*b0.y + a0.z*b0.z + a0.w*b0.w
            + a1.x*b1.x + a1.y*b1.y + a1.z*b1.z + a1.w*b1.w;
    ew_raw[e] = v;
    atomicAdd(&cnt[c], 1);
    s = (double)v; s2 = (double)v * (double)v;
  }
  for (int off = 32; off; off >>= 1) {
    s  += __shfl_down(s, off);
    s2 += __shfl_down(s2, off);
  }
  int wv = threadIdx.x >> 6;
  if ((threadIdx.x & 63) == 0) { shs[wv] = s; shs2[wv] = s2; }
  __syncthreads();
  if (threadIdx.x == 0) {
    part[blockIdx.x]           = shs[0] + shs[1] + shs[2] + shs[3];
    part[NB_EDGE + blockIdx.x] = shs2[0] + shs2[1] + shs2[2] + shs2[3];
  }
}

// ---------------- reduce edge1 partials -> red ----------------
__global__ __launch_bounds__(1024)
void redpart_kernel(const double* __restrict__ part, double* __restrict__ red)
{
  __shared__ double sh[16][2];
  int tid = threadIdx.x;
  double s = 0.0, s2 = 0.0;
  for (int i = tid; i < NB_EDGE; i += 1024) {
    s  += part[i];
    s2 += part[NB_EDGE + i];
  }
  for (int off = 32; off; off >>= 1) {
    s  += __shfl_down(s, off);
    s2 += __shfl_down(s2, off);
  }
  if ((tid & 63) == 0) { sh[tid >> 6][0] = s; sh[tid >> 6][1] = s2; }
  __syncthreads();
  if (tid == 0) {
    double a = 0.0, b = 0.0;
    for (int i = 0; i < 16; ++i) { a += sh[i][0]; b += sh[i][1]; }
    red[0] = a; red[1] = b;
  }
}

// ---------------- edge pass 2: standardize, accumulate deg ----------------
__global__ __launch_bounds__(256)
void edge2_kernel(const float* __restrict__ ew_raw, const int* __restrict__ col,
                  const double* __restrict__ red,
                  float* __restrict__ ew_std, float* __restrict__ deg)
{
  int e = blockIdx.x * 256 + threadIdx.x;
  if (e >= EE) return;
  double mean = red[0] / (double)EE;
  double var  = (red[1] - (double)EE * mean * mean) / (double)(EE - 1);
  double scl  = sqrt(1e-4 / var);
  float v = (float)(((double)ew_raw[e] - mean) * scl) + 1.0f;
  ew_std[e] = v;
  atomicAdd(&deg[col[e]], v);
}

__global__ __launch_bounds__(256)
void dinv_kernel(const float* __restrict__ deg, float* __restrict__ dinv)
{
  int n = blockIdx.x * 256 + threadIdx.x;
  if (n >= NN) return;
  float d = deg[n] + 1.0f;
  dinv[n] = d > 0.f ? 1.0f / sqrtf(fmaxf(d, 1e-12f)) : 0.f;
}

// ---------------- parallel 3-stage exclusive scan of cnt -> rowptr ----------------
// stage 1: per-block sums (coalesced)
__global__ __launch_bounds__(256)
void scan1_kernel(const int* __restrict__ cnt, int* __restrict__ bsum)
{
  __shared__ int sh[4];
  int i = blockIdx.x * 256 + threadIdx.x;
  int v = (i < NN) ? cnt[i] : 0;
  for (int off = 32; off; off >>= 1) v += __shfl_down(v, off);
  if ((threadIdx.x & 63) == 0) sh[threadIdx.x >> 6] = v;
  __syncthreads();
  if (threadIdx.x == 0) bsum[blockIdx.x] = sh[0] + sh[1] + sh[2] + sh[3];
}

// stage 2: exclusive scan of the 196 block sums (in place, one block)
__global__ __launch_bounds__(256)
void scan2_kernel(int* __restrict__ bsum)
{
  __shared__ int sh[256];
  int tid = threadIdx.x;
  int v = (tid < NB_SCAN) ? bsum[tid] : 0;
  sh[tid] = v;
  __syncthreads();
  for (int off = 1; off < 256; off <<= 1) {
    int t = (tid >= off) ? sh[tid - off] : 0;
    __syncthreads();
    sh[tid] += t;
    __syncthreads();
  }
  if (tid < NB_SCAN) bsum[tid] = sh[tid] - v;   // exclusive
}

// stage 3: block-local inclusive scan + base -> rowptr (coalesced)
__global__ __launch_bounds__(256)
void scan3_kernel(const int* __restrict__ cnt, const int* __restrict__ bsum,
                  int* __restrict__ rowptr)
{
  __shared__ int sh[256];
  int tid = threadIdx.x;
  int i = blockIdx.x * 256 + tid;
  int v = (i < NN) ? cnt[i] : 0;
  sh[tid] = v;
  __syncthreads();
  for (int off = 1; off < 256; off <<= 1) {
    int t = (tid >= off) ? sh[tid - off] : 0;
    __syncthreads();
    sh[tid] += t;
    __syncthreads();
  }
  if (i < NN) rowptr[i + 1] = bsum[blockIdx.x] + sh[tid];
  if (i == 0) rowptr[0] = 0;
}

// ---------------- edge pass 3: fill CSR (by destination), fused (src, w) ----------------
__global__ __launch_bounds__(256)
void edge3_kernel(const int* __restrict__ row, const int* __restrict__ col,
                  const float* __restrict__ ew_std, const float* __restrict__ dinv,
                  const int* __restrict__ rowptr, int* __restrict__ cursor,
                  int2* __restrict__ csr_sw)
{
  int e = blockIdx.x * 256 + threadIdx.x;
  if (e >= EE) return;
  int r = row[e], c = col[e];
  float w = dinv[r] * ew_std[e] * dinv[c];
  int pos = atomicAdd(&cursor[c], 1);
  int2 sw; sw.x = r; sw.y = __float_as_int(w);
  csr_sw[rowptr[c] + pos] = sw;
}

// ---------------- dim-256 aggregation: one wave per node, half-wave edge split ----------------
template<int MODE>
__global__ __launch_bounds__(256)
void agg256_kernel(const int* __restrict__ rowptr, const int2* __restrict__ csr_sw,
                   const unsigned short* __restrict__ gsrc,
                   const float* __restrict__ dinv, const float* __restrict__ bias,
                   const unsigned short* __restrict__ h0in,
                   unsigned short* __restrict__ h0out,
                   unsigned short* __restrict__ xout)
{
  int n = blockIdx.x * 4 + (threadIdx.x >> 6);
  if (n >= NN) return;
  const int lane = threadIdx.x & 63;
  const int half = lane >> 5;
  const int l5   = lane & 31;
  const size_t colbase = (size_t)(l5 << 3);

  float a0=0,a1=0,a2=0,a3=0,a4=0,a5=0,a6=0,a7=0;
  const int s = rowptr[n], e = rowptr[n + 1];
  int i = s + half;
  for (; i + 2 < e; i += 4) {
    int2 sw0 = csr_sw[i];
    int2 sw1 = csr_sw[i + 2];
    u16x8 v0 = *(const u16x8*)(gsrc + (size_t)sw0.x * 256 + colbase);
    u16x8 v1 = *(const u16x8*)(gsrc + (size_t)sw1.x * 256 + colbase);
    float w0 = __int_as_float(sw0.y);
    float w1 = __int_as_float(sw1.y);
    a0 += w0 * bf2f(v0[0]); a1 += w0 * bf2f(v0[1]);
    a2 += w0 * bf2f(v0[2]); a3 += w0 * bf2f(v0[3]);
    a4 += w0 * bf2f(v0[4]); a5 += w0 * bf2f(v0[5]);
    a6 += w0 * bf2f(v0[6]); a7 += w0 * bf2f(v0[7]);
    a0 += w1 * bf2f(v1[0]); a1 += w1 * bf2f(v1[1]);
    a2 += w1 * bf2f(v1[2]); a3 += w1 * bf2f(v1[3]);
    a4 += w1 * bf2f(v1[4]); a5 += w1 * bf2f(v1[5]);
    a6 += w1 * bf2f(v1[6]); a7 += w1 * bf2f(v1[7]);
  }
  if (i < e) {
    int2 sw = csr_sw[i];
    u16x8 v = *(const u16x8*)(gsrc + (size_t)sw.x * 256 + colbase);
    float w = __int_as_float(sw.y);
    a0 += w * bf2f(v[0]); a1 += w * bf2f(v[1]);
    a2 += w * bf2f(v[2]); a3 += w * bf2f(v[3]);
    a4 += w * bf2f(v[4]); a5 += w * bf2f(v[5]);
    a6 += w * bf2f(v[6]); a7 += w * bf2f(v[7]);
  }
  a0 += __shfl_xor(a0, 32); a1 += __shfl_xor(a1, 32);
  a2 += __shfl_xor(a2, 32); a3 += __shfl_xor(a3, 32);
  a4 += __shfl_xor(a4, 32); a5 += __shfl_xor(a5, 32);
  a6 += __shfl_xor(a6, 32); a7 += __shfl_xor(a7, 32);
  float f0 = half ? a4 : a0;
  float f1 = half ? a5 : a1;
  float f2 = half ? a6 : a2;
  float f3 = half ? a7 : a3;
  const int dbase = (l5 << 3) + (half << 2);
  float wd = dinv[n]; wd *= wd;
  ushort4 sv = *(const ushort4*)(gsrc + (size_t)n * 256 + dbase);
  f0 += wd * bf2f(sv.x); f1 += wd * bf2f(sv.y);
  f2 += wd * bf2f(sv.z); f3 += wd * bf2f(sv.w);
  float4 b = *(const float4*)(bias + dbase);
  f0 += b.x; f1 += b.y; f2 += b.z; f3 += b.w;
  const size_t o = (size_t)n * 256 + dbase;
  if (MODE == 0) {
    ushort4 h;
    h.x = f2bf(f0); h.y = f2bf(f1); h.z = f2bf(f2); h.w = f2bf(f3);
    *(ushort4*)(h0out + o) = h;
    ushort4 xo;
    xo.x = f2bf(fmaxf(f0, 0.f)); xo.y = f2bf(fmaxf(f1, 0.f));
    xo.z = f2bf(fmaxf(f2, 0.f)); xo.w = f2bf(fmaxf(f3, 0.f));
    *(ushort4*)(xout + o) = xo;
  } else {
    ushort4 h = *(const ushort4*)(h0in + o);
    ushort4 xo;
    xo.x = f2bf(fmaxf(f0, 0.f) + bf2f(h.x));
    xo.y = f2bf(fmaxf(f1, 0.f) + bf2f(h.y));
    xo.z = f2bf(fmaxf(f2, 0.f) + bf2f(h.z));
    xo.w = f2bf(fmaxf(f3, 0.f) + bf2f(h.w));
    *(ushort4*)(xout + o) = xo;
  }
}

// ---------------- y3[N,8] = x2[N,256] @ W3[256,7] ----------------
__global__ __launch_bounds__(256)
void gemv7_kernel(const unsigned short* __restrict__ x2, const float* __restrict__ W3,
                  float* __restrict__ y3)
{
  __shared__ float w[256 * 8];
  int tid = threadIdx.x;
  for (int i = tid; i < 2048; i += 256) {
    int k = i >> 3, c = i & 7;
    w[i] = (c < 7) ? W3[k * 7 + c] : 0.f;
  }
  __syncthreads();
  int n = blockIdx.x * 256 + tid;
  if (n >= NN) return;
  const unsigned short* xr = x2 + (size_t)n * 256;
  f32x4 accLo = {0,0,0,0}, accHi = {0,0,0,0};
  for (int k = 0; k < 256; k += 4) {
    ushort4 v = *(const ushort4*)(xr + k);
    float xs[4] = {bf2f(v.x), bf2f(v.y), bf2f(v.z), bf2f(v.w)};
#pragma unroll
    for (int j = 0; j < 4; ++j) {
      accLo += xs[j] * *(const f32x4*)&w[(k + j) * 8];
      accHi += xs[j] * *(const f32x4*)&w[(k + j) * 8 + 4];
    }
  }
  *(f32x4*)(y3 + (size_t)n * 8)     = accLo;
  *(f32x4*)(y3 + (size_t)n * 8 + 4) = accHi;
}

// ---------------- dim-7 aggregation: 8 lanes per node ----------------
__global__ __launch_bounds__(256)
void agg7_kernel(const int* __restrict__ rowptr, const int2* __restrict__ csr_sw,
                 const float* __restrict__ y3,
                 const float* __restrict__ dinv, const float* __restrict__ b3,
                 float* __restrict__ out)
{
  int n = blockIdx.x * 32 + (threadIdx.x >> 3);
  if (n >= NN) return;
  int j = threadIdx.x & 7;
  float acc = 0.f;
  int s = rowptr[n], e = rowptr[n + 1];
  for (int i = s; i < e; ++i) {
    int2 sw = csr_sw[i];
    acc += __int_as_float(sw.y) * y3[(size_t)sw.x * 8 + j];
  }
  float wd = dinv[n]; wd *= wd;
  acc += wd * y3[(size_t)n * 8 + j];
  if (j < 7) out[(size_t)n * 7 + j] = acc + b3[j];
}

// ---------------- host ----------------
extern "C" void kernel_launch(void* const* d_in, const int* in_sizes, int n_in,
                              void* d_out, int out_size, void* d_ws, size_t ws_size,
                              hipStream_t stream)
{
  const float* x   = (const float*)d_in[0];
  const int*   ei  = (const int*)d_in[1];
  const float* W1  = (const float*)d_in[2];
  const float* b1  = (const float*)d_in[3];
  const float* W2  = (const float*)d_in[4];
  const float* b2  = (const float*)d_in[5];
  const float* W3  = (const float*)d_in[6];
  const float* b3  = (const float*)d_in[7];
  const float* mw1 = (const float*)d_in[8];
  const float* mb1 = (const float*)d_in[9];
  const float* mw2 = (const float*)d_in[10];
  const float* mb2 = (const float*)d_in[11];
  const float* mw3 = (const float*)d_in[12];
  const float* mb3 = (const float*)d_in[13];
  const float* par = (const float*)d_in[14];
  const int* row = ei;
  const int* col = ei + EE;
  float* out = (float*)d_out;

  char* ws = (char*)d_ws;
  unsigned short* x_bf  = (unsigned short*)(ws + O_XBF);
  unsigned short* h0    = (unsigned short*)(ws + O_XBF);   // bf16, alias (x_bf dead after gcn1 GEMM)
  unsigned short* h1_bf = (unsigned short*)(ws + O_H1);
  unsigned short* g2_bf = (unsigned short*)(ws + O_H1);    // reuse (h1 dead)
  unsigned short* x2_bf = (unsigned short*)(ws + O_H1 + 25600000);
  unsigned short* g1_bf = (unsigned short*)(ws + O_G1);
  unsigned short* x1_bf = (unsigned short*)(ws + O_X1);
  unsigned short* h2_bf = (unsigned short*)(ws + O_H2);
  float* Lg      = (float*)(ws + O_LG);
  float* Tg      = (float*)(ws + O_TG);
  float* ew_raw  = (float*)(ws + O_EWR);
  float* y3      = (float*)(ws + O_EWR);                   // reuse (ew_raw dead)
  float* ew_std  = (float*)(ws + O_EWS);
  int2*  csr_sw  = (int2*)(ws + O_CSR);
  double* part   = (double*)(ws + O_CSR);                  // alias: dead before edge3
  unsigned short* mw1t = (unsigned short*)(ws + O_MW1T);
  unsigned short* w1t  = (unsigned short*)(ws + O_W1T);
  unsigned short* w2t  = (unsigned short*)(ws + O_W2T);
  unsigned short* mw2t = (unsigned short*)(ws + O_MW2T);
  float*  deg    = (float*)(ws + O_DEG);
  int*    cnt    = (int*)(ws + O_CNT);
  int*    cursor = (int*)(ws + O_CUR);
  double* red    = (double*)(ws + O_RED);
  int*    rowptr = (int*)(ws + O_RPT);
  float*  dinv   = (float*)(ws + O_DINV);
  int*    bsum   = (int*)(ws + O_BSUM);

  // zero: deg, cnt, cursor (contiguous)
  hipMemsetAsync(ws + O_DEG, 0, 3 * 200192, stream);

  // fp32 -> bf16 conversions
  conv_f2bf4<<<25000, 256, 0, stream>>>(x, x_bf, NN * 512 / 4);
  conv_weights<<<1920, 256, 0, stream>>>(mw1, W1, W2, mw2, mw1t, w1t, w2t, mw2t);

  // pseudo-MLP
  gemm_bf16<true,  true ><<<dim3(4, 391), 256, 0, stream>>>(x_bf, 512, mw1t, mb1, h1_bf, 512, NN, 512, 512);
  gemm_bf16<true,  true ><<<dim3(1, 391), 256, 0, stream>>>(h1_bf, 512, mw2t, mb2, h2_bf, 64, NN, 64, 512);
  logits_kernel<<<196, 256, 0, stream>>>(h2_bf, mw3, mb3, par, Lg, Tg);

  // edge weights + CSR
  edge1_kernel<<<NB_EDGE, 256, 0, stream>>>(row, col, Lg, Tg, ew_raw, cnt, part);
  redpart_kernel<<<1, 1024, 0, stream>>>(part, red);
  edge2_kernel<<<NB_EDGE, 256, 0, stream>>>(ew_raw, col, red, ew_std, deg);
  dinv_kernel<<<196, 256, 0, stream>>>(deg, dinv);
  scan1_kernel<<<NB_SCAN, 256, 0, stream>>>(cnt, bsum);
  scan2_kernel<<<1, 256, 0, stream>>>(bsum);
  scan3_kernel<<<NB_SCAN, 256, 0, stream>>>(cnt, bsum, rowptr);
  edge3_kernel<<<NB_EDGE, 256, 0, stream>>>(row, col, ew_std, dinv, rowptr, cursor, csr_sw);

  // GCN layer 0
  gemm_bf16<false, false><<<dim3(2, 391), 256, 0, stream>>>(x_bf, 512, w1t, nullptr, g1_bf, 256, NN, 256, 512);
  agg256_kernel<0><<<12500, 256, 0, stream>>>(rowptr, csr_sw, g1_bf, dinv, b1, nullptr, h0, x1_bf);
  // GCN layer 1 (+residual h0)
  gemm_bf16<false, false><<<dim3(2, 391), 256, 0, stream>>>(x1_bf, 256, w2t, nullptr, g2_bf, 256, NN, 256, 256);
  agg256_kernel<1><<<12500, 256, 0, stream>>>(rowptr, csr_sw, g2_bf, dinv, b2, h0, nullptr, x2_bf);
  // GCN layer 2 (GEMM first, aggregate in dim 7)
  gemv7_kernel<<<196, 256, 0, stream>>>(x2_bf, W3, y3);
  agg7_kernel<<<1563, 256, 0, stream>>>(rowptr, csr_sw, y3, dinv, b3, out);
}

// Round 5
// 454.786 us; speedup vs baseline: 1.9723x; 1.0517x over previous
//
#include <hip/hip_runtime.h>

#define NN 50000
#define EE 800000
#define NB_EDGE 3125   // ceil(EE/256)
#define NB_SCAN 196    // ceil(NN/256)

typedef __attribute__((ext_vector_type(4))) float f32x4;
typedef __attribute__((ext_vector_type(8))) short bf16x8;
typedef __attribute__((ext_vector_type(8))) unsigned short u16x8;

typedef const __attribute__((address_space(1))) void* gas_p;
typedef __attribute__((address_space(3))) void* las_p;

__device__ __forceinline__ float bf2f(unsigned short u) {
  union { unsigned int i; float f; } v; v.i = ((unsigned int)u) << 16; return v.f;
}
__device__ __forceinline__ unsigned short f2bf(float f) {
  union { float f; unsigned int i; } v; v.f = f;
  unsigned int u = v.i;
  return (unsigned short)((u + 0x7FFFu + ((u >> 16) & 1u)) >> 16);
}

// bijective XCD swizzle (m204): contiguous wgid chunk per XCD
__device__ __forceinline__ int xcd_swizzle(int orig, int nwg) {
  int xcd = orig & 7;
  int pos = orig >> 3;
  int q = nwg >> 3, r = nwg & 7;
  return (xcd < r ? xcd * (q + 1) : r * (q + 1) + (xcd - r) * q) + pos;
}

// ---------------- workspace layout (bytes, all 256-aligned) ----------------
constexpr size_t O_XBF  = 0;                  // x_bf [50000,512]bf16; reused as h0 [50000,256]bf16
constexpr size_t O_H1   = O_XBF + 51200000;   // h1 [50000,512]bf16; reused: g2 (25.6MB) + x2 (25.6MB)
constexpr size_t O_G1   = O_H1  + 51200000;   // g1 [50000,256]bf16
constexpr size_t O_X1   = O_G1  + 25600000;   // x1 [50000,256]bf16
constexpr size_t O_H2   = O_X1  + 25600000;   // h2 [50000,64]bf16
constexpr size_t O_LG   = O_H2  + 6400000;    // Lg [50000,8]f32
constexpr size_t O_TG   = O_LG  + 1600000;    // Tg [50000,8]f32
constexpr size_t O_EWR  = O_TG  + 1600000;    // ew_raw [E]f32; reused as y3 [50000,8]f32
constexpr size_t O_EWS  = O_EWR + 3200000;    // ew_std [E]f32
constexpr size_t O_CSR  = O_EWS + 3200000;    // csr_sw [E]int2 (aliased: edge1 partials, dead by edge3)
constexpr size_t O_MW1T = O_CSR + 6400000;    // 512*512 bf16   <- fused Bt starts here
constexpr size_t O_W1T  = O_MW1T + 524288;    // 256*512 bf16   <- contiguous after mw1t (768 rows total)
constexpr size_t O_W2T  = O_W1T  + 262144;    // 256*256 bf16
constexpr size_t O_MW2T = O_W2T  + 131072;    // 64*512 bf16
constexpr size_t O_DEG  = O_MW2T + 65536;     // [N]f32   <- zero block start
constexpr size_t O_CNT  = O_DEG  + 200192;    // [N]i32
constexpr size_t O_CUR  = O_CNT  + 200192;    // [N]i32
constexpr size_t O_RED  = O_CUR  + 200192;    // 2 doubles <- zero block end
constexpr size_t O_RPT  = O_RED  + 256;       // [N+1]i32
constexpr size_t O_DINV = O_RPT  + 200192;    // [N]f32
constexpr size_t O_BSUM = O_DINV + 200192;    // [NB_SCAN]i32 block sums

// ---------------- conversions ----------------
__global__ __launch_bounds__(256) void conv_f2bf4(const float* __restrict__ in,
                                                  unsigned short* __restrict__ out, int n4) {
  int i = blockIdx.x * 256 + threadIdx.x;
  if (i >= n4) return;
  const float4 v = ((const float4*)in)[i];
  ushort4 o; o.x = f2bf(v.x); o.y = f2bf(v.y); o.z = f2bf(v.z); o.w = f2bf(v.w);
  ((ushort4*)out)[i] = o;
}

// all four weight transposes in one dispatch
__global__ __launch_bounds__(256)
void conv_weights(const float* __restrict__ mw1, const float* __restrict__ W1,
                  const float* __restrict__ W2, const float* __restrict__ mw2,
                  unsigned short* __restrict__ mw1t, unsigned short* __restrict__ w1t,
                  unsigned short* __restrict__ w2t, unsigned short* __restrict__ mw2t)
{
  int i = blockIdx.x * 256 + threadIdx.x;
  if (i < 262144) {                 // mw1: [512,512]
    int k = i >> 9, n = i & 511;
    mw1t[(size_t)n * 512 + k] = f2bf(mw1[i]);
  } else if (i < 393216) {          // W1: [512,256]
    int j = i - 262144, k = j >> 8, n = j & 255;
    w1t[(size_t)n * 512 + k] = f2bf(W1[j]);
  } else if (i < 458752) {          // W2: [256,256]
    int j = i - 393216, k = j >> 8, n = j & 255;
    w2t[(size_t)n * 256 + k] = f2bf(W2[j]);
  } else if (i < 491520) {          // mw2: [512,64]
    int j = i - 458752, k = j >> 6, n = j & 63;
    mw2t[(size_t)n * 512 + k] = f2bf(mw2[j]);
  }
}

// ---------------- GEMM core macro-shared pieces ----------------
// 128x128 tile, BK=32, 4 waves, global_load_lds with XOR kslot swizzle.
#define GEMM_BODY(A, lda, Bt, ldb_K, M, Ncols, K, bm, bn)                          \
  __shared__ unsigned short ldsA[128 * 32];                                        \
  __shared__ unsigned short ldsB[128 * 32];                                        \
  const int tid  = threadIdx.x;                                                    \
  const int lane = tid & 63;                                                       \
  const int wid  = tid >> 6;                                                       \
  const int wm   = (wid >> 1) << 6;                                                \
  const int wn   = (wid & 1) << 6;                                                 \
  f32x4 acc[4][4] = {};                                                            \
  const int srow  = lane >> 2;                                                     \
  const int sslot = lane & 3;                                                      \
  for (int k0 = 0; k0 < K; k0 += 32) {                                             \
    if (k0) __syncthreads();                                                       \
    _Pragma("unroll")                                                              \
    for (int c = 0; c < 2; ++c) {                                                  \
      const int chunk = c * 4 + wid;                                               \
      const int row   = chunk * 16 + srow;                                         \
      const int ks    = sslot ^ ((row >> 1) & 3);                                  \
      int ga = bm + row; ga = ga < M ? ga : M - 1;                                 \
      int gb = bn + row; gb = gb < Ncols ? gb : Ncols - 1;                         \
      const char* srcA = (const char*)A  + ((size_t)ga * lda + k0) * 2 + ks * 16;  \
      const char* srcB = (const char*)Bt + ((size_t)gb * ldb_K + k0) * 2 + ks * 16;\
      __builtin_amdgcn_global_load_lds((gas_p)srcA, (las_p)(ldsA + chunk * 512), 16, 0, 0); \
      __builtin_amdgcn_global_load_lds((gas_p)srcB, (las_p)(ldsB + chunk * 512), 16, 0, 0); \
    }                                                                              \
    __syncthreads();                                                               \
    const int q   = lane >> 4;                                                     \
    const int r15 = lane & 15;                                                     \
    bf16x8 af[4], bfr[4];                                                          \
    _Pragma("unroll")                                                              \
    for (int m = 0; m < 4; ++m) {                                                  \
      const int ra = wm + m * 16 + r15;                                            \
      af[m]  = *(const bf16x8*)(ldsA + ra * 32 + (q ^ ((ra >> 1) & 3)) * 8);       \
      const int rb = wn + m * 16 + r15;                                            \
      bfr[m] = *(const bf16x8*)(ldsB + rb * 32 + (q ^ ((rb >> 1) & 3)) * 8);       \
    }                                                                              \
    _Pragma("unroll")                                                              \
    for (int m = 0; m < 4; ++m)                                                    \
      _Pragma("unroll")                                                            \
      for (int n = 0; n < 4; ++n)                                                  \
        acc[m][n] = __builtin_amdgcn_mfma_f32_16x16x32_bf16(af[m], bfr[n], acc[m][n], 0, 0, 0); \
  }

// ---------------- generic GEMM: C[M,ldc] = A[M,lda] * Bt[N,K]^T ----------------
template<bool RELU, bool BIAS>
__global__ __launch_bounds__(256)
void gemm_bf16(const unsigned short* __restrict__ A, int lda,
               const unsigned short* __restrict__ Bt,
               const float* __restrict__ bias,
               unsigned short* __restrict__ C, int ldc,
               int M, int N, int K)
{
  const int nwg  = gridDim.x * gridDim.y;
  const int wgid = xcd_swizzle(blockIdx.y * gridDim.x + blockIdx.x, nwg);
  const int bn   = (wgid % gridDim.x) << 7;
  const int bm   = (wgid / gridDim.x) << 7;

  GEMM_BODY(A, lda, Bt, K, M, N, K, bm, bn)

  const int q   = lane >> 4;
  const int r15 = lane & 15;
#pragma unroll
  for (int m = 0; m < 4; ++m) {
#pragma unroll
    for (int n = 0; n < 4; ++n) {
      const int gc = bn + wn + n * 16 + r15;
#pragma unroll
      for (int i = 0; i < 4; ++i) {
        const int gr = bm + wm + m * 16 + q * 4 + i;
        if (gr < M && gc < N) {
          float f = acc[m][n][i];
          if (BIAS) f += bias[gc];
          if (RELU) f = fmaxf(f, 0.f);
          C[(size_t)gr * ldc + gc] = f2bf(f);
        }
      }
    }
  }
}

// ---------------- fused MLP1+GCN1 GEMM: A=x_bf [M,512], Bt=[768,512] ----------------
// cols 0..511  -> h1 = relu(. + mb1), ldc 512
// cols 512..767-> g1 = .            , ldc 256
__global__ __launch_bounds__(256)
void gemm_fused(const unsigned short* __restrict__ A,
                const unsigned short* __restrict__ Bt,
                const float* __restrict__ mb1,
                unsigned short* __restrict__ h1,
                unsigned short* __restrict__ g1,
                int M)
{
  const int nwg  = gridDim.x * gridDim.y;
  const int wgid = xcd_swizzle(blockIdx.y * gridDim.x + blockIdx.x, nwg);
  const int bnt  = wgid % gridDim.x;
  const int bn   = bnt << 7;
  const int bm   = (wgid / gridDim.x) << 7;

  GEMM_BODY(A, 512, Bt, 512, M, 768, 512, bm, bn)

  const int q   = lane >> 4;
  const int r15 = lane & 15;
  if (bnt < 4) {   // h1 epilogue: bias + relu
#pragma unroll
    for (int m = 0; m < 4; ++m) {
#pragma unroll
      for (int n = 0; n < 4; ++n) {
        const int gc = bn + wn + n * 16 + r15;
        const float b = mb1[gc];
#pragma unroll
        for (int i = 0; i < 4; ++i) {
          const int gr = bm + wm + m * 16 + q * 4 + i;
          if (gr < M) h1[(size_t)gr * 512 + gc] = f2bf(fmaxf(acc[m][n][i] + b, 0.f));
        }
      }
    }
  } else {         // g1 epilogue: plain
#pragma unroll
    for (int m = 0; m < 4; ++m) {
#pragma unroll
      for (int n = 0; n < 4; ++n) {
        const int gc = bn - 512 + wn + n * 16 + r15;
#pragma unroll
        for (int i = 0; i < 4; ++i) {
          const int gr = bm + wm + m * 16 + q * 4 + i;
          if (gr < M) g1[(size_t)gr * 256 + gc] = f2bf(acc[m][n][i]);
        }
      }
    }
  }
}

// ---------------- logits (h2[N,64] @ mw3[64,7] + mb3) and T = L @ relu(2*P) ----------------
__global__ __launch_bounds__(256)
void logits_kernel(const unsigned short* __restrict__ h2, const float* __restrict__ mw3,
                   const float* __restrict__ mb3, const float* __restrict__ par,
                   float* __restrict__ Lg, float* __restrict__ Tg)
{
  __shared__ float w[64 * 8];
  __shared__ float P[64];
  int tid = threadIdx.x;
  for (int i = tid; i < 512; i += 256) {
    int k = i >> 3, c = i & 7;
    w[i] = (c < 7) ? mw3[k * 7 + c] : 0.f;
  }
  if (tid < 64) {
    int d = tid >> 3, c = tid & 7;
    P[tid] = (d < 7 && c < 7) ? fmaxf(2.0f * par[d * 7 + c], 0.f) : 0.f;
  }
  __syncthreads();
  int n = blockIdx.x * 256 + tid;
  if (n >= NN) return;
  const unsigned short* hr = h2 + (size_t)n * 64;
  f32x4 L0 = {0,0,0,0}, L1 = {0,0,0,0};
  for (int k = 0; k < 64; k += 4) {
    ushort4 v = *(const ushort4*)(hr + k);
    float xs[4] = {bf2f(v.x), bf2f(v.y), bf2f(v.z), bf2f(v.w)};
#pragma unroll
    for (int j = 0; j < 4; ++j) {
      L0 += xs[j] * *(const f32x4*)&w[(k + j) * 8];
      L1 += xs[j] * *(const f32x4*)&w[(k + j) * 8 + 4];
    }
  }
  float Ls[8] = {L0[0], L0[1], L0[2], L0[3], L1[0], L1[1], L1[2], 0.f};
#pragma unroll
  for (int c = 0; c < 7; ++c) Ls[c] += mb3[c];
  f32x4 T0 = {0,0,0,0}, T1 = {0,0,0,0};
#pragma unroll
  for (int d = 0; d < 7; ++d) {
    T0 += Ls[d] * *(const f32x4*)&P[d * 8];
    T1 += Ls[d] * *(const f32x4*)&P[d * 8 + 4];
  }
  f32x4 o0 = {Ls[0], Ls[1], Ls[2], Ls[3]};
  f32x4 o1 = {Ls[4], Ls[5], Ls[6], 0.f};
  *(f32x4*)(Lg + (size_t)n * 8)     = o0;
  *(f32x4*)(Lg + (size_t)n * 8 + 4) = o1;
  *(f32x4*)(Tg + (size_t)n * 8)     = T0;
  *(f32x4*)(Tg + (size_t)n * 8 + 4) = T1;
}

// ---------------- edge pass 1 ----------------
__global__ __launch_bounds__(256)
void edge1_kernel(const int* __restrict__ row, const int* __restrict__ col,
                  const float* __restrict__ Lg, const float* __restrict__ Tg,
                  float* __restrict__ ew_raw, int* __restrict__ cnt,
                  double* __restrict__ part)
{
  __shared__ double shs[4], shs2[4];
  int e = blockIdx.x * 256 + threadIdx.x;
  double s = 0.0, s2 = 0.0;
  if (e < EE) {
    int r = row[e], c = col[e];
    float4 a0 = *(const float4*)(Lg + (size_t)r * 8);
    float4 a1 = *(const float4*)(Lg + (size_t)r * 8 + 4);
    float4 b0 = *(const float4*)(Tg + (size_t)c * 8);
    float4 b1 = *(const float4*)(Tg + (size_t)c * 8 + 4);
    float v = a0.x*b0.x + a0.y*b0.y + a0.z*b0.z + a0.w*b0.w
            + a1.x*b1.x + a1.y*b1.y + a1.z*b1.z + a1.w*b1.w;
    ew_raw[e] = v;
    atomicAdd(&cnt[c], 1);
    s = (double)v; s2 = (double)v * (double)v;
  }
  for (int off = 32; off; off >>= 1) {
    s  += __shfl_down(s, off);
    s2 += __shfl_down(s2, off);
  }
  int wv = threadIdx.x >> 6;
  if ((threadIdx.x & 63) == 0) { shs[wv] = s; shs2[wv] = s2; }
  __syncthreads();
  if (threadIdx.x == 0) {
    part[blockIdx.x]           = shs[0] + shs[1] + shs[2] + shs[3];
    part[NB_EDGE + blockIdx.x] = shs2[0] + shs2[1] + shs2[2] + shs2[3];
  }
}

// ---------------- reduce edge1 partials -> red ----------------
__global__ __launch_bounds__(1024)
void redpart_kernel(const double* __restrict__ part, double* __restrict__ red)
{
  __shared__ double sh[16][2];
  int tid = threadIdx.x;
  double s = 0.0, s2 = 0.0;
  for (int i = tid; i < NB_EDGE; i += 1024) {
    s  += part[i];
    s2 += part[NB_EDGE + i];
  }
  for (int off = 32; off; off >>= 1) {
    s  += __shfl_down(s, off);
    s2 += __shfl_down(s2, off);
  }
  if ((tid & 63) == 0) { sh[tid >> 6][0] = s; sh[tid >> 6][1] = s2; }
  __syncthreads();
  if (tid == 0) {
    double a = 0.0, b = 0.0;
    for (int i = 0; i < 16; ++i) { a += sh[i][0]; b += sh[i][1]; }
    red[0] = a; red[1] = b;
  }
}

// ---------------- edge pass 2 ----------------
__global__ __launch_bounds__(256)
void edge2_kernel(const float* __restrict__ ew_raw, const int* __restrict__ col,
                  const double* __restrict__ red,
                  float* __restrict__ ew_std, float* __restrict__ deg)
{
  int e = blockIdx.x * 256 + threadIdx.x;
  if (e >= EE) return;
  double mean = red[0] / (double)EE;
  double var  = (red[1] - (double)EE * mean * mean) / (double)(EE - 1);
  double scl  = sqrt(1e-4 / var);
  float v = (float)(((double)ew_raw[e] - mean) * scl) + 1.0f;
  ew_std[e] = v;
  atomicAdd(&deg[col[e]], v);
}

__global__ __launch_bounds__(256)
void dinv_kernel(const float* __restrict__ deg, float* __restrict__ dinv)
{
  int n = blockIdx.x * 256 + threadIdx.x;
  if (n >= NN) return;
  float d = deg[n] + 1.0f;
  dinv[n] = d > 0.f ? 1.0f / sqrtf(fmaxf(d, 1e-12f)) : 0.f;
}

// ---------------- parallel 3-stage exclusive scan of cnt -> rowptr ----------------
__global__ __launch_bounds__(256)
void scan1_kernel(const int* __restrict__ cnt, int* __restrict__ bsum)
{
  __shared__ int sh[4];
  int i = blockIdx.x * 256 + threadIdx.x;
  int v = (i < NN) ? cnt[i] : 0;
  for (int off = 32; off; off >>= 1) v += __shfl_down(v, off);
  if ((threadIdx.x & 63) == 0) sh[threadIdx.x >> 6] = v;
  __syncthreads();
  if (threadIdx.x == 0) bsum[blockIdx.x] = sh[0] + sh[1] + sh[2] + sh[3];
}

__global__ __launch_bounds__(256)
void scan2_kernel(int* __restrict__ bsum)
{
  __shared__ int sh[256];
  int tid = threadIdx.x;
  int v = (tid < NB_SCAN) ? bsum[tid] : 0;
  sh[tid] = v;
  __syncthreads();
  for (int off = 1; off < 256; off <<= 1) {
    int t = (tid >= off) ? sh[tid - off] : 0;
    __syncthreads();
    sh[tid] += t;
    __syncthreads();
  }
  if (tid < NB_SCAN) bsum[tid] = sh[tid] - v;   // exclusive
}

__global__ __launch_bounds__(256)
void scan3_kernel(const int* __restrict__ cnt, const int* __restrict__ bsum,
                  int* __restrict__ rowptr)
{
  __shared__ int sh[256];
  int tid = threadIdx.x;
  int i = blockIdx.x * 256 + tid;
  int v = (i < NN) ? cnt[i] : 0;
  sh[tid] = v;
  __syncthreads();
  for (int off = 1; off < 256; off <<= 1) {
    int t = (tid >= off) ? sh[tid - off] : 0;
    __syncthreads();
    sh[tid] += t;
    __syncthreads();
  }
  if (i < NN) rowptr[i + 1] = bsum[blockIdx.x] + sh[tid];
  if (i == 0) rowptr[0] = 0;
}

// ---------------- edge pass 3: fill CSR (by destination), fused (src, w) ----------------
__global__ __launch_bounds__(256)
void edge3_kernel(const int* __restrict__ row, const int* __restrict__ col,
                  const float* __restrict__ ew_std, const float* __restrict__ dinv,
                  const int* __restrict__ rowptr, int* __restrict__ cursor,
                  int2* __restrict__ csr_sw)
{
  int e = blockIdx.x * 256 + threadIdx.x;
  if (e >= EE) return;
  int r = row[e], c = col[e];
  float w = dinv[r] * ew_std[e] * dinv[c];
  int pos = atomicAdd(&cursor[c], 1);
  int2 sw; sw.x = r; sw.y = __float_as_int(w);
  csr_sw[rowptr[c] + pos] = sw;
}

// ---------------- dim-256 aggregation: one wave per node, half-wave edge split ----------------
template<int MODE>
__global__ __launch_bounds__(256)
void agg256_kernel(const int* __restrict__ rowptr, const int2* __restrict__ csr_sw,
                   const unsigned short* __restrict__ gsrc,
                   const float* __restrict__ dinv, const float* __restrict__ bias,
                   const unsigned short* __restrict__ h0in,
                   unsigned short* __restrict__ h0out,
                   unsigned short* __restrict__ xout)
{
  int n = blockIdx.x * 4 + (threadIdx.x >> 6);
  if (n >= NN) return;
  const int lane = threadIdx.x & 63;
  const int half = lane >> 5;
  const int l5   = lane & 31;
  const size_t colbase = (size_t)(l5 << 3);

  float a0=0,a1=0,a2=0,a3=0,a4=0,a5=0,a6=0,a7=0;
  const int s = rowptr[n], e = rowptr[n + 1];
  int i = s + half;
  for (; i + 2 < e; i += 4) {
    int2 sw0 = csr_sw[i];
    int2 sw1 = csr_sw[i + 2];
    u16x8 v0 = *(const u16x8*)(gsrc + (size_t)sw0.x * 256 + colbase);
    u16x8 v1 = *(const u16x8*)(gsrc + (size_t)sw1.x * 256 + colbase);
    float w0 = __int_as_float(sw0.y);
    float w1 = __int_as_float(sw1.y);
    a0 += w0 * bf2f(v0[0]); a1 += w0 * bf2f(v0[1]);
    a2 += w0 * bf2f(v0[2]); a3 += w0 * bf2f(v0[3]);
    a4 += w0 * bf2f(v0[4]); a5 += w0 * bf2f(v0[5]);
    a6 += w0 * bf2f(v0[6]); a7 += w0 * bf2f(v0[7]);
    a0 += w1 * bf2f(v1[0]); a1 += w1 * bf2f(v1[1]);
    a2 += w1 * bf2f(v1[2]); a3 += w1 * bf2f(v1[3]);
    a4 += w1 * bf2f(v1[4]); a5 += w1 * bf2f(v1[5]);
    a6 += w1 * bf2f(v1[6]); a7 += w1 * bf2f(v1[7]);
  }
  if (i < e) {
    int2 sw = csr_sw[i];
    u16x8 v = *(const u16x8*)(gsrc + (size_t)sw.x * 256 + colbase);
    float w = __int_as_float(sw.y);
    a0 += w * bf2f(v[0]); a1 += w * bf2f(v[1]);
    a2 += w * bf2f(v[2]); a3 += w * bf2f(v[3]);
    a4 += w * bf2f(v[4]); a5 += w * bf2f(v[5]);
    a6 += w * bf2f(v[6]); a7 += w * bf2f(v[7]);
  }
  a0 += __shfl_xor(a0, 32); a1 += __shfl_xor(a1, 32);
  a2 += __shfl_xor(a2, 32); a3 += __shfl_xor(a3, 32);
  a4 += __shfl_xor(a4, 32); a5 += __shfl_xor(a5, 32);
  a6 += __shfl_xor(a6, 32); a7 += __shfl_xor(a7, 32);
  float f0 = half ? a4 : a0;
  float f1 = half ? a5 : a1;
  float f2 = half ? a6 : a2;
  float f3 = half ? a7 : a3;
  const int dbase = (l5 << 3) + (half << 2);
  float wd = dinv[n]; wd *= wd;
  ushort4 sv = *(const ushort4*)(gsrc + (size_t)n * 256 + dbase);
  f0 += wd * bf2f(sv.x); f1 += wd * bf2f(sv.y);
  f2 += wd * bf2f(sv.z); f3 += wd * bf2f(sv.w);
  float4 b = *(const float4*)(bias + dbase);
  f0 += b.x; f1 += b.y; f2 += b.z; f3 += b.w;
  const size_t o = (size_t)n * 256 + dbase;
  if (MODE == 0) {
    ushort4 h;
    h.x = f2bf(f0); h.y = f2bf(f1); h.z = f2bf(f2); h.w = f2bf(f3);
    *(ushort4*)(h0out + o) = h;
    ushort4 xo;
    xo.x = f2bf(fmaxf(f0, 0.f)); xo.y = f2bf(fmaxf(f1, 0.f));
    xo.z = f2bf(fmaxf(f2, 0.f)); xo.w = f2bf(fmaxf(f3, 0.f));
    *(ushort4*)(xout + o) = xo;
  } else {
    ushort4 h = *(const ushort4*)(h0in + o);
    ushort4 xo;
    xo.x = f2bf(fmaxf(f0, 0.f) + bf2f(h.x));
    xo.y = f2bf(fmaxf(f1, 0.f) + bf2f(h.y));
    xo.z = f2bf(fmaxf(f2, 0.f) + bf2f(h.z));
    xo.w = f2bf(fmaxf(f3, 0.f) + bf2f(h.w));
    *(ushort4*)(xout + o) = xo;
  }
}

// ---------------- y3[N,8] = x2[N,256] @ W3[256,7] ----------------
__global__ __launch_bounds__(256)
void gemv7_kernel(const unsigned short* __restrict__ x2, const float* __restrict__ W3,
                  float* __restrict__ y3)
{
  __shared__ float w[256 * 8];
  int tid = threadIdx.x;
  for (int i = tid; i < 2048; i += 256) {
    int k = i >> 3, c = i & 7;
    w[i] = (c < 7) ? W3[k * 7 + c] : 0.f;
  }
  __syncthreads();
  int n = blockIdx.x * 256 + tid;
  if (n >= NN) return;
  const unsigned short* xr = x2 + (size_t)n * 256;
  f32x4 accLo = {0,0,0,0}, accHi = {0,0,0,0};
  for (int k = 0; k < 256; k += 4) {
    ushort4 v = *(const ushort4*)(xr + k);
    float xs[4] = {bf2f(v.x), bf2f(v.y), bf2f(v.z), bf2f(v.w)};
#pragma unroll
    for (int j = 0; j < 4; ++j) {
      accLo += xs[j] * *(const f32x4*)&w[(k + j) * 8];
      accHi += xs[j] * *(const f32x4*)&w[(k + j) * 8 + 4];
    }
  }
  *(f32x4*)(y3 + (size_t)n * 8)     = accLo;
  *(f32x4*)(y3 + (size_t)n * 8 + 4) = accHi;
}

// ---------------- dim-7 aggregation: 8 lanes per node ----------------
__global__ __launch_bounds__(256)
void agg7_kernel(const int* __restrict__ rowptr, const int2* __restrict__ csr_sw,
                 const float* __restrict__ y3,
                 const float* __restrict__ dinv, const float* __restrict__ b3,
                 float* __restrict__ out)
{
  int n = blockIdx.x * 32 + (threadIdx.x >> 3);
  if (n >= NN) return;
  int j = threadIdx.x & 7;
  float acc = 0.f;
  int s = rowptr[n], e = rowptr[n + 1];
  for (int i = s; i < e; ++i) {
    int2 sw = csr_sw[i];
    acc += __int_as_float(sw.y) * y3[(size_t)sw.x * 8 + j];
  }
  float wd = dinv[n]; wd *= wd;
  acc += wd * y3[(size_t)n * 8 + j];
  if (j < 7) out[(size_t)n * 7 + j] = acc + b3[j];
}

// ---------------- host ----------------
extern "C" void kernel_launch(void* const* d_in, const int* in_sizes, int n_in,
                              void* d_out, int out_size, void* d_ws, size_t ws_size,
                              hipStream_t stream)
{
  const float* x   = (const float*)d_in[0];
  const int*   ei  = (const int*)d_in[1];
  const float* W1  = (const float*)d_in[2];
  const float* b1  = (const float*)d_in[3];
  const float* W2  = (const float*)d_in[4];
  const float* b2  = (const float*)d_in[5];
  const float* W3  = (const float*)d_in[6];
  const float* b3  = (const float*)d_in[7];
  const float* mw1 = (const float*)d_in[8];
  const float* mb1 = (const float*)d_in[9];
  const float* mw2 = (const float*)d_in[10];
  const float* mb2 = (const float*)d_in[11];
  const float* mw3 = (const float*)d_in[12];
  const float* mb3 = (const float*)d_in[13];
  const float* par = (const float*)d_in[14];
  const int* row = ei;
  const int* col = ei + EE;
  float* out = (float*)d_out;

  char* ws = (char*)d_ws;
  unsigned short* x_bf  = (unsigned short*)(ws + O_XBF);
  unsigned short* h0    = (unsigned short*)(ws + O_XBF);   // bf16, alias (x_bf dead after fused GEMM)
  unsigned short* h1_bf = (unsigned short*)(ws + O_H1);
  unsigned short* g2_bf = (unsigned short*)(ws + O_H1);    // reuse (h1 dead)
  unsigned short* x2_bf = (unsigned short*)(ws + O_H1 + 25600000);
  unsigned short* g1_bf = (unsigned short*)(ws + O_G1);
  unsigned short* x1_bf = (unsigned short*)(ws + O_X1);
  unsigned short* h2_bf = (unsigned short*)(ws + O_H2);
  float* Lg      = (float*)(ws + O_LG);
  float* Tg      = (float*)(ws + O_TG);
  float* ew_raw  = (float*)(ws + O_EWR);
  float* y3      = (float*)(ws + O_EWR);                   // reuse (ew_raw dead)
  float* ew_std  = (float*)(ws + O_EWS);
  int2*  csr_sw  = (int2*)(ws + O_CSR);
  double* part   = (double*)(ws + O_CSR);                  // alias: dead before edge3
  unsigned short* mw1t = (unsigned short*)(ws + O_MW1T);   // fused Bt = [mw1t; w1t], 768 rows
  unsigned short* w1t  = (unsigned short*)(ws + O_W1T);
  unsigned short* w2t  = (unsigned short*)(ws + O_W2T);
  unsigned short* mw2t = (unsigned short*)(ws + O_MW2T);
  float*  deg    = (float*)(ws + O_DEG);
  int*    cnt    = (int*)(ws + O_CNT);
  int*    cursor = (int*)(ws + O_CUR);
  double* red    = (double*)(ws + O_RED);
  int*    rowptr = (int*)(ws + O_RPT);
  float*  dinv   = (float*)(ws + O_DINV);
  int*    bsum   = (int*)(ws + O_BSUM);

  // zero: deg, cnt, cursor (contiguous)
  hipMemsetAsync(ws + O_DEG, 0, 3 * 200192, stream);

  // fp32 -> bf16 conversions
  conv_f2bf4<<<25000, 256, 0, stream>>>(x, x_bf, NN * 512 / 4);
  conv_weights<<<1920, 256, 0, stream>>>(mw1, W1, W2, mw2, mw1t, w1t, w2t, mw2t);

  // fused MLP1 + GCN1 GEMM (h1 and g1 from one read of x_bf)
  gemm_fused<<<dim3(6, 391), 256, 0, stream>>>(x_bf, mw1t, mb1, h1_bf, g1_bf, NN);
  // MLP layer 2
  gemm_bf16<true,  true ><<<dim3(1, 391), 256, 0, stream>>>(h1_bf, 512, mw2t, mb2, h2_bf, 64, NN, 64, 512);
  logits_kernel<<<196, 256, 0, stream>>>(h2_bf, mw3, mb3, par, Lg, Tg);

  // edge weights + CSR
  edge1_kernel<<<NB_EDGE, 256, 0, stream>>>(row, col, Lg, Tg, ew_raw, cnt, part);
  redpart_kernel<<<1, 1024, 0, stream>>>(part, red);
  edge2_kernel<<<NB_EDGE, 256, 0, stream>>>(ew_raw, col, red, ew_std, deg);
  dinv_kernel<<<196, 256, 0, stream>>>(deg, dinv);
  scan1_kernel<<<NB_SCAN, 256, 0, stream>>>(cnt, bsum);
  scan2_kernel<<<1, 256, 0, stream>>>(bsum);
  scan3_kernel<<<NB_SCAN, 256, 0, stream>>>(cnt, bsum, rowptr);
  edge3_kernel<<<NB_EDGE, 256, 0, stream>>>(row, col, ew_std, dinv, rowptr, cursor, csr_sw);

  // GCN layer 0 aggregation (g1 already computed by fused GEMM)
  agg256_kernel<0><<<12500, 256, 0, stream>>>(rowptr, csr_sw, g1_bf, dinv, b1, nullptr, h0, x1_bf);
  // GCN layer 1 (+residual h0)
  gemm_bf16<false, false><<<dim3(2, 391), 256, 0, stream>>>(x1_bf, 256, w2t, nullptr, g2_bf, 256, NN, 256, 256);
  agg256_kernel<1><<<12500, 256, 0, stream>>>(rowptr, csr_sw, g2_bf, dinv, b2, h0, nullptr, x2_bf);
  // GCN layer 2 (GEMM first, aggregate in dim 7)
  gemv7_kernel<<<196, 256, 0, stream>>>(x2_bf, W3, y3);
  agg7_kernel<<<1563, 256, 0, stream>>>(rowptr, csr_sw, y3, dinv, b3, out);
}

// Round 6
// 447.823 us; speedup vs baseline: 2.0030x; 1.0155x over previous
//
#include <hip/hip_runtime.h>

#define NN 50000
#define EE 800000
#define NB_EDGE 3125   // ceil(EE/256)
#define NB_SCAN 196    // ceil(NN/256)

typedef __attribute__((ext_vector_type(4))) float f32x4;
typedef __attribute__((ext_vector_type(8))) short bf16x8;
typedef __attribute__((ext_vector_type(8))) unsigned short u16x8;

typedef const __attribute__((address_space(1))) void* gas_p;
typedef __attribute__((address_space(3))) void* las_p;

__device__ __forceinline__ float bf2f(unsigned short u) {
  union { unsigned int i; float f; } v; v.i = ((unsigned int)u) << 16; return v.f;
}
__device__ __forceinline__ unsigned short f2bf(float f) {
  union { float f; unsigned int i; } v; v.f = f;
  unsigned int u = v.i;
  return (unsigned short)((u + 0x7FFFu + ((u >> 16) & 1u)) >> 16);
}

// bijective XCD swizzle (m204): contiguous wgid chunk per XCD
__device__ __forceinline__ int xcd_swizzle(int orig, int nwg) {
  int xcd = orig & 7;
  int pos = orig >> 3;
  int q = nwg >> 3, r = nwg & 7;
  return (xcd < r ? xcd * (q + 1) : r * (q + 1) + (xcd - r) * q) + pos;
}

// ---------------- workspace layout (bytes, all 256-aligned) ----------------
constexpr size_t O_XBF  = 0;                  // x_bf [50000,512]bf16; reused as h0 [50000,256]bf16
constexpr size_t O_H1   = O_XBF + 51200000;   // h1 [50000,512]bf16; reused: g2 (25.6MB) + x2 (25.6MB)
constexpr size_t O_G1   = O_H1  + 51200000;   // g1 [50000,256]bf16
constexpr size_t O_X1   = O_G1  + 25600000;   // x1 [50000,256]bf16
constexpr size_t O_H2   = O_X1  + 25600000;   // h2 [50000,64]bf16
constexpr size_t O_LG   = O_H2  + 6400000;    // Lg [50000,8]f32
constexpr size_t O_TG   = O_LG  + 1600000;    // Tg [50000,8]f32
constexpr size_t O_EWR  = O_TG  + 1600000;    // ew_raw [E]f32; reused as y3 [50000,8]f32
constexpr size_t O_EWS  = O_EWR + 3200000;    // ew_std [E]f32
constexpr size_t O_CSR  = O_EWS + 3200000;    // csr_sw [E]int2 (aliased: edge1 partials, dead by edge3)
constexpr size_t O_MW1T = O_CSR + 6400000;    // 512*512 bf16   <- fused Bt starts here
constexpr size_t O_W1T  = O_MW1T + 524288;    // 256*512 bf16   <- contiguous after mw1t (768 rows total)
constexpr size_t O_W2T  = O_W1T  + 262144;    // 256*256 bf16
constexpr size_t O_MW2T = O_W2T  + 131072;    // 64*512 bf16
constexpr size_t O_DEG  = O_MW2T + 65536;     // [N]f32   <- zero block start
constexpr size_t O_CNT  = O_DEG  + 200192;    // [N]i32
constexpr size_t O_CUR  = O_CNT  + 200192;    // [N]i32
constexpr size_t O_RED  = O_CUR  + 200192;    // 2 doubles <- zero block end
constexpr size_t O_RPT  = O_RED  + 256;       // [N+1]i32
constexpr size_t O_DINV = O_RPT  + 200192;    // [N]f32
constexpr size_t O_BSUM = O_DINV + 200192;    // [NB_SCAN]i32 block sums

// ---------------- conversions ----------------
__global__ __launch_bounds__(256) void conv_f2bf4(const float* __restrict__ in,
                                                  unsigned short* __restrict__ out, int n4) {
  int i = blockIdx.x * 256 + threadIdx.x;
  if (i >= n4) return;
  const float4 v = ((const float4*)in)[i];
  ushort4 o; o.x = f2bf(v.x); o.y = f2bf(v.y); o.z = f2bf(v.z); o.w = f2bf(v.w);
  ((ushort4*)out)[i] = o;
}

// all four weight transposes in one dispatch
__global__ __launch_bounds__(256)
void conv_weights(const float* __restrict__ mw1, const float* __restrict__ W1,
                  const float* __restrict__ W2, const float* __restrict__ mw2,
                  unsigned short* __restrict__ mw1t, unsigned short* __restrict__ w1t,
                  unsigned short* __restrict__ w2t, unsigned short* __restrict__ mw2t)
{
  int i = blockIdx.x * 256 + threadIdx.x;
  if (i < 262144) {                 // mw1: [512,512]
    int k = i >> 9, n = i & 511;
    mw1t[(size_t)n * 512 + k] = f2bf(mw1[i]);
  } else if (i < 393216) {          // W1: [512,256]
    int j = i - 262144, k = j >> 8, n = j & 255;
    w1t[(size_t)n * 512 + k] = f2bf(W1[j]);
  } else if (i < 458752) {          // W2: [256,256]
    int j = i - 393216, k = j >> 8, n = j & 255;
    w2t[(size_t)n * 256 + k] = f2bf(W2[j]);
  } else if (i < 491520) {          // mw2: [512,64]
    int j = i - 458752, k = j >> 6, n = j & 63;
    mw2t[(size_t)n * 512 + k] = f2bf(mw2[j]);
  }
}

// ---------------- GEMM core: 128x128 tile, BK=64, 4 waves ----------------
// LDS row = 64 bf16 = 128B = 8 x 16B slots. XOR swizzle slot^= (row&7), applied
// identically on the pre-swizzled global source and the ds_read (rule #21).
// Requires K % 64 == 0.
#define GEMM_BODY(A, lda, Bt, ldb_K, M, Ncols, K, bm, bn)                          \
  __shared__ unsigned short ldsA[128 * 64];                                        \
  __shared__ unsigned short ldsB[128 * 64];                                        \
  const int tid  = threadIdx.x;                                                    \
  const int lane = tid & 63;                                                       \
  const int wid  = tid >> 6;                                                       \
  const int wm   = (wid >> 1) << 6;                                                \
  const int wn   = (wid & 1) << 6;                                                 \
  f32x4 acc[4][4] = {};                                                            \
  const int srow8 = lane >> 3;                                                     \
  const int sks   = (lane & 7) ^ srow8;   /* pre-swizzled source slot */           \
  for (int k0 = 0; k0 < K; k0 += 64) {                                             \
    if (k0) __syncthreads();                                                       \
    _Pragma("unroll")                                                              \
    for (int r = 0; r < 4; ++r) {                                                  \
      const int row = r * 32 + wid * 8 + srow8;                                    \
      int ga = bm + row; ga = ga < M ? ga : M - 1;                                 \
      int gb = bn + row; gb = gb < Ncols ? gb : Ncols - 1;                         \
      const char* srcA = (const char*)A  + ((size_t)ga * lda + k0) * 2 + sks * 16; \
      const char* srcB = (const char*)Bt + ((size_t)gb * ldb_K + k0) * 2 + sks * 16;\
      __builtin_amdgcn_global_load_lds((gas_p)srcA, (las_p)(ldsA + (r * 32 + wid * 8) * 64), 16, 0, 0); \
      __builtin_amdgcn_global_load_lds((gas_p)srcB, (las_p)(ldsB + (r * 32 + wid * 8) * 64), 16, 0, 0); \
    }                                                                              \
    __syncthreads();                                                               \
    const int q   = lane >> 4;                                                     \
    const int r15 = lane & 15;                                                     \
    _Pragma("unroll")                                                              \
    for (int kk = 0; kk < 2; ++kk) {                                               \
      bf16x8 af[4], bfr[4];                                                        \
      _Pragma("unroll")                                                            \
      for (int m = 0; m < 4; ++m) {                                                \
        const int ra = wm + m * 16 + r15;                                          \
        af[m]  = *(const bf16x8*)(ldsA + ra * 64 + (((kk << 2) + q) ^ (ra & 7)) * 8); \
        const int rb = wn + m * 16 + r15;                                          \
        bfr[m] = *(const bf16x8*)(ldsB + rb * 64 + (((kk << 2) + q) ^ (rb & 7)) * 8); \
      }                                                                            \
      _Pragma("unroll")                                                            \
      for (int m = 0; m < 4; ++m)                                                  \
        _Pragma("unroll")                                                          \
        for (int n = 0; n < 4; ++n)                                                \
          acc[m][n] = __builtin_amdgcn_mfma_f32_16x16x32_bf16(af[m], bfr[n], acc[m][n], 0, 0, 0); \
    }                                                                              \
  }

// ---------------- generic GEMM: C[M,ldc] = A[M,lda] * Bt[N,K]^T ----------------
template<bool RELU, bool BIAS>
__global__ __launch_bounds__(256)
void gemm_bf16(const unsigned short* __restrict__ A, int lda,
               const unsigned short* __restrict__ Bt,
               const float* __restrict__ bias,
               unsigned short* __restrict__ C, int ldc,
               int M, int N, int K)
{
  const int nwg  = gridDim.x * gridDim.y;
  const int wgid = xcd_swizzle(blockIdx.y * gridDim.x + blockIdx.x, nwg);
  const int bn   = (wgid % gridDim.x) << 7;
  const int bm   = (wgid / gridDim.x) << 7;

  GEMM_BODY(A, lda, Bt, K, M, N, K, bm, bn)

  const int q   = lane >> 4;
  const int r15 = lane & 15;
#pragma unroll
  for (int m = 0; m < 4; ++m) {
#pragma unroll
    for (int n = 0; n < 4; ++n) {
      const int gc = bn + wn + n * 16 + r15;
#pragma unroll
      for (int i = 0; i < 4; ++i) {
        const int gr = bm + wm + m * 16 + q * 4 + i;
        if (gr < M && gc < N) {
          float f = acc[m][n][i];
          if (BIAS) f += bias[gc];
          if (RELU) f = fmaxf(f, 0.f);
          C[(size_t)gr * ldc + gc] = f2bf(f);
        }
      }
    }
  }
}

// ---------------- fused MLP1+GCN1 GEMM: A=x_bf [M,512], Bt=[768,512] ----------------
__global__ __launch_bounds__(256)
void gemm_fused(const unsigned short* __restrict__ A,
                const unsigned short* __restrict__ Bt,
                const float* __restrict__ mb1,
                unsigned short* __restrict__ h1,
                unsigned short* __restrict__ g1,
                int M)
{
  const int nwg  = gridDim.x * gridDim.y;
  const int wgid = xcd_swizzle(blockIdx.y * gridDim.x + blockIdx.x, nwg);
  const int bnt  = wgid % gridDim.x;
  const int bn   = bnt << 7;
  const int bm   = (wgid / gridDim.x) << 7;

  GEMM_BODY(A, 512, Bt, 512, M, 768, 512, bm, bn)

  const int q   = lane >> 4;
  const int r15 = lane & 15;
  if (bnt < 4) {   // h1 epilogue: bias + relu
#pragma unroll
    for (int m = 0; m < 4; ++m) {
#pragma unroll
      for (int n = 0; n < 4; ++n) {
        const int gc = bn + wn + n * 16 + r15;
        const float b = mb1[gc];
#pragma unroll
        for (int i = 0; i < 4; ++i) {
          const int gr = bm + wm + m * 16 + q * 4 + i;
          if (gr < M) h1[(size_t)gr * 512 + gc] = f2bf(fmaxf(acc[m][n][i] + b, 0.f));
        }
      }
    }
  } else {         // g1 epilogue: plain
#pragma unroll
    for (int m = 0; m < 4; ++m) {
#pragma unroll
      for (int n = 0; n < 4; ++n) {
        const int gc = bn - 512 + wn + n * 16 + r15;
#pragma unroll
        for (int i = 0; i < 4; ++i) {
          const int gr = bm + wm + m * 16 + q * 4 + i;
          if (gr < M) g1[(size_t)gr * 256 + gc] = f2bf(acc[m][n][i]);
        }
      }
    }
  }
}

// ---------------- logits (h2[N,64] @ mw3[64,7] + mb3) and T = L @ relu(2*P) ----------------
__global__ __launch_bounds__(256)
void logits_kernel(const unsigned short* __restrict__ h2, const float* __restrict__ mw3,
                   const float* __restrict__ mb3, const float* __restrict__ par,
                   float* __restrict__ Lg, float* __restrict__ Tg)
{
  __shared__ float w[64 * 8];
  __shared__ float P[64];
  int tid = threadIdx.x;
  for (int i = tid; i < 512; i += 256) {
    int k = i >> 3, c = i & 7;
    w[i] = (c < 7) ? mw3[k * 7 + c] : 0.f;
  }
  if (tid < 64) {
    int d = tid >> 3, c = tid & 7;
    P[tid] = (d < 7 && c < 7) ? fmaxf(2.0f * par[d * 7 + c], 0.f) : 0.f;
  }
  __syncthreads();
  int n = blockIdx.x * 256 + tid;
  if (n >= NN) return;
  const unsigned short* hr = h2 + (size_t)n * 64;
  f32x4 L0 = {0,0,0,0}, L1 = {0,0,0,0};
  for (int k = 0; k < 64; k += 4) {
    ushort4 v = *(const ushort4*)(hr + k);
    float xs[4] = {bf2f(v.x), bf2f(v.y), bf2f(v.z), bf2f(v.w)};
#pragma unroll
    for (int j = 0; j < 4; ++j) {
      L0 += xs[j] * *(const f32x4*)&w[(k + j) * 8];
      L1 += xs[j] * *(const f32x4*)&w[(k + j) * 8 + 4];
    }
  }
  float Ls[8] = {L0[0], L0[1], L0[2], L0[3], L1[0], L1[1], L1[2], 0.f};
#pragma unroll
  for (int c = 0; c < 7; ++c) Ls[c] += mb3[c];
  f32x4 T0 = {0,0,0,0}, T1 = {0,0,0,0};
#pragma unroll
  for (int d = 0; d < 7; ++d) {
    T0 += Ls[d] * *(const f32x4*)&P[d * 8];
    T1 += Ls[d] * *(const f32x4*)&P[d * 8 + 4];
  }
  f32x4 o0 = {Ls[0], Ls[1], Ls[2], Ls[3]};
  f32x4 o1 = {Ls[4], Ls[5], Ls[6], 0.f};
  *(f32x4*)(Lg + (size_t)n * 8)     = o0;
  *(f32x4*)(Lg + (size_t)n * 8 + 4) = o1;
  *(f32x4*)(Tg + (size_t)n * 8)     = T0;
  *(f32x4*)(Tg + (size_t)n * 8 + 4) = T1;
}

// ---------------- edge pass 1 ----------------
__global__ __launch_bounds__(256)
void edge1_kernel(const int* __restrict__ row, const int* __restrict__ col,
                  const float* __restrict__ Lg, const float* __restrict__ Tg,
                  float* __restrict__ ew_raw, int* __restrict__ cnt,
                  double* __restrict__ part)
{
  __shared__ double shs[4], shs2[4];
  int e = blockIdx.x * 256 + threadIdx.x;
  double s = 0.0, s2 = 0.0;
  if (e < EE) {
    int r = row[e], c = col[e];
    float4 a0 = *(const float4*)(Lg + (size_t)r * 8);
    float4 a1 = *(const float4*)(Lg + (size_t)r * 8 + 4);
    float4 b0 = *(const float4*)(Tg + (size_t)c * 8);
    float4 b1 = *(const float4*)(Tg + (size_t)c * 8 + 4);
    float v = a0.x*b0.x + a0.y*b0.y + a0.z*b0.z + a0.w*b0.w
            + a1.x*b1.x + a1.y*b1.y + a1.z*b1.z + a1.w*b1.w;
    ew_raw[e] = v;
    atomicAdd(&cnt[c], 1);
    s = (double)v; s2 = (double)v * (double)v;
  }
  for (int off = 32; off; off >>= 1) {
    s  += __shfl_down(s, off);
    s2 += __shfl_down(s2, off);
  }
  int wv = threadIdx.x >> 6;
  if ((threadIdx.x & 63) == 0) { shs[wv] = s; shs2[wv] = s2; }
  __syncthreads();
  if (threadIdx.x == 0) {
    part[blockIdx.x]           = shs[0] + shs[1] + shs[2] + shs[3];
    part[NB_EDGE + blockIdx.x] = shs2[0] + shs2[1] + shs2[2] + shs2[3];
  }
}

// ---------------- reduce edge1 partials -> red ----------------
__global__ __launch_bounds__(1024)
void redpart_kernel(const double* __restrict__ part, double* __restrict__ red)
{
  __shared__ double sh[16][2];
  int tid = threadIdx.x;
  double s = 0.0, s2 = 0.0;
  for (int i = tid; i < NB_EDGE; i += 1024) {
    s  += part[i];
    s2 += part[NB_EDGE + i];
  }
  for (int off = 32; off; off >>= 1) {
    s  += __shfl_down(s, off);
    s2 += __shfl_down(s2, off);
  }
  if ((tid & 63) == 0) { sh[tid >> 6][0] = s; sh[tid >> 6][1] = s2; }
  __syncthreads();
  if (tid == 0) {
    double a = 0.0, b = 0.0;
    for (int i = 0; i < 16; ++i) { a += sh[i][0]; b += sh[i][1]; }
    red[0] = a; red[1] = b;
  }
}

// ---------------- edge pass 2 ----------------
__global__ __launch_bounds__(256)
void edge2_kernel(const float* __restrict__ ew_raw, const int* __restrict__ col,
                  const double* __restrict__ red,
                  float* __restrict__ ew_std, float* __restrict__ deg)
{
  int e = blockIdx.x * 256 + threadIdx.x;
  if (e >= EE) return;
  double mean = red[0] / (double)EE;
  double var  = (red[1] - (double)EE * mean * mean) / (double)(EE - 1);
  double scl  = sqrt(1e-4 / var);
  float v = (float)(((double)ew_raw[e] - mean) * scl) + 1.0f;
  ew_std[e] = v;
  atomicAdd(&deg[col[e]], v);
}

__global__ __launch_bounds__(256)
void dinv_kernel(const float* __restrict__ deg, float* __restrict__ dinv)
{
  int n = blockIdx.x * 256 + threadIdx.x;
  if (n >= NN) return;
  float d = deg[n] + 1.0f;
  dinv[n] = d > 0.f ? 1.0f / sqrtf(fmaxf(d, 1e-12f)) : 0.f;
}

// ---------------- parallel 3-stage exclusive scan of cnt -> rowptr ----------------
__global__ __launch_bounds__(256)
void scan1_kernel(const int* __restrict__ cnt, int* __restrict__ bsum)
{
  __shared__ int sh[4];
  int i = blockIdx.x * 256 + threadIdx.x;
  int v = (i < NN) ? cnt[i] : 0;
  for (int off = 32; off; off >>= 1) v += __shfl_down(v, off);
  if ((threadIdx.x & 63) == 0) sh[threadIdx.x >> 6] = v;
  __syncthreads();
  if (threadIdx.x == 0) bsum[blockIdx.x] = sh[0] + sh[1] + sh[2] + sh[3];
}

__global__ __launch_bounds__(256)
void scan2_kernel(int* __restrict__ bsum)
{
  __shared__ int sh[256];
  int tid = threadIdx.x;
  int v = (tid < NB_SCAN) ? bsum[tid] : 0;
  sh[tid] = v;
  __syncthreads();
  for (int off = 1; off < 256; off <<= 1) {
    int t = (tid >= off) ? sh[tid - off] : 0;
    __syncthreads();
    sh[tid] += t;
    __syncthreads();
  }
  if (tid < NB_SCAN) bsum[tid] = sh[tid] - v;   // exclusive
}

__global__ __launch_bounds__(256)
void scan3_kernel(const int* __restrict__ cnt, const int* __restrict__ bsum,
                  int* __restrict__ rowptr)
{
  __shared__ int sh[256];
  int tid = threadIdx.x;
  int i = blockIdx.x * 256 + tid;
  int v = (i < NN) ? cnt[i] : 0;
  sh[tid] = v;
  __syncthreads();
  for (int off = 1; off < 256; off <<= 1) {
    int t = (tid >= off) ? sh[tid - off] : 0;
    __syncthreads();
    sh[tid] += t;
    __syncthreads();
  }
  if (i < NN) rowptr[i + 1] = bsum[blockIdx.x] + sh[tid];
  if (i == 0) rowptr[0] = 0;
}

// ---------------- edge pass 3: fill CSR (by destination), fused (src, w) ----------------
__global__ __launch_bounds__(256)
void edge3_kernel(const int* __restrict__ row, const int* __restrict__ col,
                  const float* __restrict__ ew_std, const float* __restrict__ dinv,
                  const int* __restrict__ rowptr, int* __restrict__ cursor,
                  int2* __restrict__ csr_sw)
{
  int e = blockIdx.x * 256 + threadIdx.x;
  if (e >= EE) return;
  int r = row[e], c = col[e];
  float w = dinv[r] * ew_std[e] * dinv[c];
  int pos = atomicAdd(&cursor[c], 1);
  int2 sw; sw.x = r; sw.y = __float_as_int(w);
  csr_sw[rowptr[c] + pos] = sw;
}

// ---------------- dim-256 aggregation: wave/node, half-wave split, 4 gathers in flight ----
template<int MODE>
__global__ __launch_bounds__(256)
void agg256_kernel(const int* __restrict__ rowptr, const int2* __restrict__ csr_sw,
                   const unsigned short* __restrict__ gsrc,
                   const float* __restrict__ dinv, const float* __restrict__ bias,
                   const unsigned short* __restrict__ h0in,
                   unsigned short* __restrict__ h0out,
                   unsigned short* __restrict__ xout)
{
  int n = blockIdx.x * 4 + (threadIdx.x >> 6);
  if (n >= NN) return;
  const int lane = threadIdx.x & 63;
  const int half = lane >> 5;
  const int l5   = lane & 31;
  const size_t colbase = (size_t)(l5 << 3);

  float a0=0,a1=0,a2=0,a3=0,a4=0,a5=0,a6=0,a7=0;
  const int s = rowptr[n], e = rowptr[n + 1];
  int i = s + half;
  for (; i + 6 < e; i += 8) {                 // 4 edges per half-wave in flight
    int2 sw0 = csr_sw[i];
    int2 sw1 = csr_sw[i + 2];
    int2 sw2 = csr_sw[i + 4];
    int2 sw3 = csr_sw[i + 6];
    u16x8 v0 = *(const u16x8*)(gsrc + (size_t)sw0.x * 256 + colbase);
    u16x8 v1 = *(const u16x8*)(gsrc + (size_t)sw1.x * 256 + colbase);
    u16x8 v2 = *(const u16x8*)(gsrc + (size_t)sw2.x * 256 + colbase);
    u16x8 v3 = *(const u16x8*)(gsrc + (size_t)sw3.x * 256 + colbase);
    float w0 = __int_as_float(sw0.y);
    float w1 = __int_as_float(sw1.y);
    float w2 = __int_as_float(sw2.y);
    float w3 = __int_as_float(sw3.y);
    a0 += w0 * bf2f(v0[0]); a1 += w0 * bf2f(v0[1]);
    a2 += w0 * bf2f(v0[2]); a3 += w0 * bf2f(v0[3]);
    a4 += w0 * bf2f(v0[4]); a5 += w0 * bf2f(v0[5]);
    a6 += w0 * bf2f(v0[6]); a7 += w0 * bf2f(v0[7]);
    a0 += w1 * bf2f(v1[0]); a1 += w1 * bf2f(v1[1]);
    a2 += w1 * bf2f(v1[2]); a3 += w1 * bf2f(v1[3]);
    a4 += w1 * bf2f(v1[4]); a5 += w1 * bf2f(v1[5]);
    a6 += w1 * bf2f(v1[6]); a7 += w1 * bf2f(v1[7]);
    a0 += w2 * bf2f(v2[0]); a1 += w2 * bf2f(v2[1]);
    a2 += w2 * bf2f(v2[2]); a3 += w2 * bf2f(v2[3]);
    a4 += w2 * bf2f(v2[4]); a5 += w2 * bf2f(v2[5]);
    a6 += w2 * bf2f(v2[6]); a7 += w2 * bf2f(v2[7]);
    a0 += w3 * bf2f(v3[0]); a1 += w3 * bf2f(v3[1]);
    a2 += w3 * bf2f(v3[2]); a3 += w3 * bf2f(v3[3]);
    a4 += w3 * bf2f(v3[4]); a5 += w3 * bf2f(v3[5]);
    a6 += w3 * bf2f(v3[6]); a7 += w3 * bf2f(v3[7]);
  }
  for (; i < e; i += 2) {
    int2 sw = csr_sw[i];
    u16x8 v = *(const u16x8*)(gsrc + (size_t)sw.x * 256 + colbase);
    float w = __int_as_float(sw.y);
    a0 += w * bf2f(v[0]); a1 += w * bf2f(v[1]);
    a2 += w * bf2f(v[2]); a3 += w * bf2f(v[3]);
    a4 += w * bf2f(v[4]); a5 += w * bf2f(v[5]);
    a6 += w * bf2f(v[6]); a7 += w * bf2f(v[7]);
  }
  a0 += __shfl_xor(a0, 32); a1 += __shfl_xor(a1, 32);
  a2 += __shfl_xor(a2, 32); a3 += __shfl_xor(a3, 32);
  a4 += __shfl_xor(a4, 32); a5 += __shfl_xor(a5, 32);
  a6 += __shfl_xor(a6, 32); a7 += __shfl_xor(a7, 32);
  float f0 = half ? a4 : a0;
  float f1 = half ? a5 : a1;
  float f2 = half ? a6 : a2;
  float f3 = half ? a7 : a3;
  const int dbase = (l5 << 3) + (half << 2);
  float wd = dinv[n]; wd *= wd;
  ushort4 sv = *(const ushort4*)(gsrc + (size_t)n * 256 + dbase);
  f0 += wd * bf2f(sv.x); f1 += wd * bf2f(sv.y);
  f2 += wd * bf2f(sv.z); f3 += wd * bf2f(sv.w);
  float4 b = *(const float4*)(bias + dbase);
  f0 += b.x; f1 += b.y; f2 += b.z; f3 += b.w;
  const size_t o = (size_t)n * 256 + dbase;
  if (MODE == 0) {
    ushort4 h;
    h.x = f2bf(f0); h.y = f2bf(f1); h.z = f2bf(f2); h.w = f2bf(f3);
    *(ushort4*)(h0out + o) = h;
    ushort4 xo;
    xo.x = f2bf(fmaxf(f0, 0.f)); xo.y = f2bf(fmaxf(f1, 0.f));
    xo.z = f2bf(fmaxf(f2, 0.f)); xo.w = f2bf(fmaxf(f3, 0.f));
    *(ushort4*)(xout + o) = xo;
  } else {
    ushort4 h = *(const ushort4*)(h0in + o);
    ushort4 xo;
    xo.x = f2bf(fmaxf(f0, 0.f) + bf2f(h.x));
    xo.y = f2bf(fmaxf(f1, 0.f) + bf2f(h.y));
    xo.z = f2bf(fmaxf(f2, 0.f) + bf2f(h.z));
    xo.w = f2bf(fmaxf(f3, 0.f) + bf2f(h.w));
    *(ushort4*)(xout + o) = xo;
  }
}

// ---------------- y3[N,8] = x2[N,256] @ W3[256,7] ----------------
__global__ __launch_bounds__(256)
void gemv7_kernel(const unsigned short* __restrict__ x2, const float* __restrict__ W3,
                  float* __restrict__ y3)
{
  __shared__ float w[256 * 8];
  int tid = threadIdx.x;
  for (int i = tid; i < 2048; i += 256) {
    int k = i >> 3, c = i & 7;
    w[i] = (c < 7) ? W3[k * 7 + c] : 0.f;
  }
  __syncthreads();
  int n = blockIdx.x * 256 + tid;
  if (n >= NN) return;
  const unsigned short* xr = x2 + (size_t)n * 256;
  f32x4 accLo = {0,0,0,0}, accHi = {0,0,0,0};
  for (int k = 0; k < 256; k += 4) {
    ushort4 v = *(const ushort4*)(xr + k);
    float xs[4] = {bf2f(v.x), bf2f(v.y), bf2f(v.z), bf2f(v.w)};
#pragma unroll
    for (int j = 0; j < 4; ++j) {
      accLo += xs[j] * *(const f32x4*)&w[(k + j) * 8];
      accHi += xs[j] * *(const f32x4*)&w[(k + j) * 8 + 4];
    }
  }
  *(f32x4*)(y3 + (size_t)n * 8)     = accLo;
  *(f32x4*)(y3 + (size_t)n * 8 + 4) = accHi;
}

// ---------------- dim-7 aggregation: 8 lanes per node ----------------
__global__ __launch_bounds__(256)
void agg7_kernel(const int* __restrict__ rowptr, const int2* __restrict__ csr_sw,
                 const float* __restrict__ y3,
                 const float* __restrict__ dinv, const float* __restrict__ b3,
                 float* __restrict__ out)
{
  int n = blockIdx.x * 32 + (threadIdx.x >> 3);
  if (n >= NN) return;
  int j = threadIdx.x & 7;
  float acc = 0.f;
  int s = rowptr[n], e = rowptr[n + 1];
  for (int i = s; i < e; ++i) {
    int2 sw = csr_sw[i];
    acc += __int_as_float(sw.y) * y3[(size_t)sw.x * 8 + j];
  }
  float wd = dinv[n]; wd *= wd;
  acc += wd * y3[(size_t)n * 8 + j];
  if (j < 7) out[(size_t)n * 7 + j] = acc + b3[j];
}

// ---------------- host ----------------
extern "C" void kernel_launch(void* const* d_in, const int* in_sizes, int n_in,
                              void* d_out, int out_size, void* d_ws, size_t ws_size,
                              hipStream_t stream)
{
  const float* x   = (const float*)d_in[0];
  const int*   ei  = (const int*)d_in[1];
  const float* W1  = (const float*)d_in[2];
  const float* b1  = (const float*)d_in[3];
  const float* W2  = (const float*)d_in[4];
  const float* b2  = (const float*)d_in[5];
  const float* W3  = (const float*)d_in[6];
  const float* b3  = (const float*)d_in[7];
  const float* mw1 = (const float*)d_in[8];
  const float* mb1 = (const float*)d_in[9];
  const float* mw2 = (const float*)d_in[10];
  const float* mb2 = (const float*)d_in[11];
  const float* mw3 = (const float*)d_in[12];
  const float* mb3 = (const float*)d_in[13];
  const float* par = (const float*)d_in[14];
  const int* row = ei;
  const int* col = ei + EE;
  float* out = (float*)d_out;

  char* ws = (char*)d_ws;
  unsigned short* x_bf  = (unsigned short*)(ws + O_XBF);
  unsigned short* h0    = (unsigned short*)(ws + O_XBF);   // bf16, alias (x_bf dead after fused GEMM)
  unsigned short* h1_bf = (unsigned short*)(ws + O_H1);
  unsigned short* g2_bf = (unsigned short*)(ws + O_H1);    // reuse (h1 dead)
  unsigned short* x2_bf = (unsigned short*)(ws + O_H1 + 25600000);
  unsigned short* g1_bf = (unsigned short*)(ws + O_G1);
  unsigned short* x1_bf = (unsigned short*)(ws + O_X1);
  unsigned short* h2_bf = (unsigned short*)(ws + O_H2);
  float* Lg      = (float*)(ws + O_LG);
  float* Tg      = (float*)(ws + O_TG);
  float* ew_raw  = (float*)(ws + O_EWR);
  float* y3      = (float*)(ws + O_EWR);                   // reuse (ew_raw dead)
  float* ew_std  = (float*)(ws + O_EWS);
  int2*  csr_sw  = (int2*)(ws + O_CSR);
  double* part   = (double*)(ws + O_CSR);                  // alias: dead before edge3
  unsigned short* mw1t = (unsigned short*)(ws + O_MW1T);   // fused Bt = [mw1t; w1t], 768 rows
  unsigned short* w1t  = (unsigned short*)(ws + O_W1T);
  unsigned short* w2t  = (unsigned short*)(ws + O_W2T);
  unsigned short* mw2t = (unsigned short*)(ws + O_MW2T);
  float*  deg    = (float*)(ws + O_DEG);
  int*    cnt    = (int*)(ws + O_CNT);
  int*    cursor = (int*)(ws + O_CUR);
  double* red    = (double*)(ws + O_RED);
  int*    rowptr = (int*)(ws + O_RPT);
  float*  dinv   = (float*)(ws + O_DINV);
  int*    bsum   = (int*)(ws + O_BSUM);

  // zero: deg, cnt, cursor (contiguous)
  hipMemsetAsync(ws + O_DEG, 0, 3 * 200192, stream);

  // fp32 -> bf16 conversions
  conv_f2bf4<<<25000, 256, 0, stream>>>(x, x_bf, NN * 512 / 4);
  conv_weights<<<1920, 256, 0, stream>>>(mw1, W1, W2, mw2, mw1t, w1t, w2t, mw2t);

  // fused MLP1 + GCN1 GEMM (h1 and g1 from one read of x_bf)
  gemm_fused<<<dim3(6, 391), 256, 0, stream>>>(x_bf, mw1t, mb1, h1_bf, g1_bf, NN);
  // MLP layer 2
  gemm_bf16<true,  true ><<<dim3(1, 391), 256, 0, stream>>>(h1_bf, 512, mw2t, mb2, h2_bf, 64, NN, 64, 512);
  logits_kernel<<<196, 256, 0, stream>>>(h2_bf, mw3, mb3, par, Lg, Tg);

  // edge weights + CSR
  edge1_kernel<<<NB_EDGE, 256, 0, stream>>>(row, col, Lg, Tg, ew_raw, cnt, part);
  redpart_kernel<<<1, 1024, 0, stream>>>(part, red);
  edge2_kernel<<<NB_EDGE, 256, 0, stream>>>(ew_raw, col, red, ew_std, deg);
  dinv_kernel<<<196, 256, 0, stream>>>(deg, dinv);
  scan1_kernel<<<NB_SCAN, 256, 0, stream>>>(cnt, bsum);
  scan2_kernel<<<1, 256, 0, stream>>>(bsum);
  scan3_kernel<<<NB_SCAN, 256, 0, stream>>>(cnt, bsum, rowptr);
  edge3_kernel<<<NB_EDGE, 256, 0, stream>>>(row, col, ew_std, dinv, rowptr, cursor, csr_sw);

  // GCN layer 0 aggregation (g1 already computed by fused GEMM)
  agg256_kernel<0><<<12500, 256, 0, stream>>>(rowptr, csr_sw, g1_bf, dinv, b1, nullptr, h0, x1_bf);
  // GCN layer 1 (+residual h0)
  gemm_bf16<false, false><<<dim3(2, 391), 256, 0, stream>>>(x1_bf, 256, w2t, nullptr, g2_bf, 256, NN, 256, 256);
  agg256_kernel<1><<<12500, 256, 0, stream>>>(rowptr, csr_sw, g2_bf, dinv, b2, h0, nullptr, x2_bf);
  // GCN layer 2 (GEMM first, aggregate in dim 7)
  gemv7_kernel<<<196, 256, 0, stream>>>(x2_bf, W3, y3);
  agg7_kernel<<<1563, 256, 0, stream>>>(rowptr, csr_sw, y3, dinv, b3, out);
}